// Round 5
// baseline (178.248 us; speedup 1.0000x reference)
//
#include <hip/hip_runtime.h>
#include <hip/hip_bf16.h>
#include <math.h>

// Problem constants: x [8,64,64,64] fp32 NCHW, W_std [64,64,3,3] fp32 OIHW.
#define BB 8
#define CC 64
#define HH 64
#define WW 64
#define NPIX (HH*WW)   // 4096
#define LOG2E 1.44269504088896340736f

typedef __attribute__((ext_vector_type(8))) short bf16x8;            // bf16 A/B frag
typedef __attribute__((ext_vector_type(8))) _Float16 half8;          // fp16 A/B frag (K=32)
typedef __attribute__((ext_vector_type(4))) _Float16 half4;          // fp16 A/B frag (K=16)
typedef __attribute__((ext_vector_type(4))) float floatx4;           // MFMA C/D frag
typedef __attribute__((ext_vector_type(8))) unsigned short ushort8;  // 16B unit

__device__ inline unsigned short f2bf(float x) {
  __hip_bfloat16 h = __float2bfloat16(x);
  return *reinterpret_cast<unsigned short*>(&h);
}
__device__ inline unsigned short f2bf_fast(float x) {
  const unsigned u = __float_as_uint(x);
  return (unsigned short)((u + 0x8000u) >> 16);
}
__device__ inline float bf2f(unsigned short u) {
  __hip_bfloat16 h = *reinterpret_cast<__hip_bfloat16*>(&u);
  return __bfloat162float(h);
}
__device__ inline unsigned short f2h(float x) {
  _Float16 h = (_Float16)x;
  return *reinterpret_cast<unsigned short*>(&h);
}
__device__ inline float h2f(unsigned short u) {
  _Float16 h = *reinterpret_cast<_Float16*>(&u);
  return (float)h;
}

// XOR swizzle for K/Q rows: 16B chunks permuted within each 128B row.
__device__ inline int swzoff(int n, int c) {
  return (((c >> 3) ^ (n & 7)) << 3) | (c & 7);
}
// V^T swizzle: b64-granular (round 18 — measured 4.75M -> 0 conflicts).
__device__ inline int swzvslot(int key, int c) {
  return ((((key >> 2) ^ (c & 15)) << 2)) | (key & 3);
}

// 16B global -> LDS DMA (per-lane global scatter OK; LDS dest = base+lane*16)
#define GLD_LDS16(gp, lp)                                                     \
  __builtin_amdgcn_global_load_lds(                                           \
      (const __attribute__((address_space(1))) void*)(gp),                    \
      (__attribute__((address_space(3))) void*)(lp), 16, 0, 0)

// ---------------------------------------------------------------------------
// wprep: WT[tap][o][c] bf16 hi/lo, depthwise Laplacian folded in.
// ---------------------------------------------------------------------------
__global__ __launch_bounds__(256) void wprep_kernel(
    const float* __restrict__ w,
    unsigned short* __restrict__ wth, unsigned short* __restrict__ wtl) {
  const int idx = blockIdx.x * 256 + threadIdx.x;   // 9*64*64 = 36864
  const int c   = idx & 63;
  const int o   = (idx >> 6) & 63;
  const int tap = idx >> 12;
  float v = w[((o * 64 + c) * 9) + tap];
  if (o == c) {
    const float lapk[9] = {0.f, 1.f, 0.f, 1.f, -4.f, 1.f, 0.f, 1.f, 0.f};
    v += lapk[tap];
  }
  const unsigned short hi = f2bf(v);
  wth[(tap * 64 + o) * 64 + c] = hi;
  wtl[(tap * 64 + o) * 64 + c] = f2bf(v - bf2f(hi));
}

// ---------------------------------------------------------------------------
// conv_mfma: implicit-GEMM conv. Round 20: SINGLE-PHASE staging — DMA all
// 3 fp32 x-rows (48KB) into the XS region itself, drain ONCE, copy each
// thread's 48 values to registers, barrier, convert/write the swizzled
// bf16 hi/lo layout in place. 6 barriers -> 3, XLf gone, LDS 64 -> 48KB
// -> 3 blocks/CU.
// ---------------------------------------------------------------------------
__global__ __launch_bounds__(256, 3) void conv_mfma(
    const float* __restrict__ xin,
    const unsigned short* __restrict__ wth,
    const unsigned short* __restrict__ wtl,
    unsigned short* __restrict__ fh, unsigned short* __restrict__ fl,
    unsigned short* __restrict__ fv) {
  __shared__ __align__(16) unsigned short XS[6 * 4096];  // 48KB

  const int tid  = threadIdx.x;
  const int lane = tid & 63;
  const int wave = tid >> 6;
  const int r16  = lane & 15;
  const int quad = lane >> 4;
  const int y = blockIdx.x, b = blockIdx.y;
  const int px = tid & 63, cp = tid >> 6;

  // ---- stage: DMA 3 rows fp32 [c][x] into XS bytes [r*16KB ...] ----
  float* XSf = (float*)XS;
  const float* xb = xin + (size_t)b * CC * NPIX;
#pragma unroll
  for (int r = 0; r < 3; ++r) {
    const int yy = min(max(y - 1 + r, 0), HH - 1);
    const float* xrow = xb + yy * WW;
#pragma unroll
    for (int j = 0; j < 4; ++j) {
      const int cb = (wave * 4 + j) * 4;        // 4 channel-rows per DMA
      const int cl = cb + (lane >> 4);
      const float* g = xrow + (size_t)cl * NPIX + ((lane & 15) << 2);
      GLD_LDS16(g, (char*)XSf + r * 16384 + cb * 256 + lane * 16);
    }
  }
  __syncthreads();                              // single DMA drain

  // ---- copy this thread's 48 values to regs (fp32 region dies next) ----
  float xv[3][16];
#pragma unroll
  for (int r = 0; r < 3; ++r)
#pragma unroll
    for (int j = 0; j < 16; ++j)
      xv[r][j] = XSf[r * 4096 + (cp * 16 + j) * 64 + px];
  __syncthreads();                              // all reads done

  // ---- convert/write swizzled bf16 hi/lo in place ----
#pragma unroll
  for (int r = 0; r < 3; ++r) {
    ushort8 vh[2], vl[2];
#pragma unroll
    for (int j = 0; j < 16; ++j) {
      const float v = xv[r][j];
      const unsigned short hh = f2bf(v);
      vh[j >> 3][j & 7] = hh;
      vl[j >> 3][j & 7] = f2bf(v - bf2f(hh));
    }
    unsigned short* xsh = XS + r * 4096 + px * 64;
    unsigned short* xsl = XS + (3 + r) * 4096 + px * 64;
#pragma unroll
    for (int k = 0; k < 2; ++k) {
      const int ch = cp * 2 + k;
      const int off = ((ch ^ (px & 7)) << 3);
      *(ushort8*)(xsh + off) = vh[k];
      *(ushort8*)(xsl + off) = vl[k];
    }
  }
  __syncthreads();                              // XS ready

  floatx4 acc[4];
#pragma unroll
  for (int t = 0; t < 4; ++t) acc[t] = (floatx4){0.f, 0.f, 0.f, 0.f};
  const bf16x8 ZF = {0, 0, 0, 0, 0, 0, 0, 0};
  const int og = wave * 16 + r16;

#pragma unroll
  for (int tap = 0; tap < 9; ++tap) {
    const int ky = tap / 3, kx = tap % 3;
    const int yy = y + ky - 1;
    if (yy < 0 || yy >= HH) continue;
    const unsigned short* wt = wth + ((tap * 64 + og) << 6);
    const unsigned short* wl = wtl + ((tap * 64 + og) << 6);
    const bf16x8 Wh0 = *(const bf16x8*)(wt + quad * 8);
    const bf16x8 Wh1 = *(const bf16x8*)(wt + 32 + quad * 8);
    const bf16x8 Wl0 = *(const bf16x8*)(wl + quad * 8);
    const bf16x8 Wl1 = *(const bf16x8*)(wl + 32 + quad * 8);
#pragma unroll
    for (int t = 0; t < 4; ++t) {
      const int px2 = t * 16 + r16 + kx - 1;
      const bool ok = (px2 >= 0) && (px2 < WW);
      const int pxc = ok ? px2 : 0;
      const int bh = ky * 4096 + pxc * 64;
      const int bl = bh + 3 * 4096;
      const int o0 = ((quad ^ (pxc & 7)) << 3);
      const int o1 = (((4 + quad) ^ (pxc & 7)) << 3);
      bf16x8 Ah0 = *(const bf16x8*)(XS + bh + o0);
      bf16x8 Ah1 = *(const bf16x8*)(XS + bh + o1);
      bf16x8 Al0 = *(const bf16x8*)(XS + bl + o0);
      bf16x8 Al1 = *(const bf16x8*)(XS + bl + o1);
      if (!ok) { Ah0 = ZF; Ah1 = ZF; Al0 = ZF; Al1 = ZF; }
      acc[t] = __builtin_amdgcn_mfma_f32_16x16x32_bf16(Ah0, Wh0, acc[t], 0, 0, 0);
      acc[t] = __builtin_amdgcn_mfma_f32_16x16x32_bf16(Ah1, Wh1, acc[t], 0, 0, 0);
      acc[t] = __builtin_amdgcn_mfma_f32_16x16x32_bf16(Ah0, Wl0, acc[t], 0, 0, 0);
      acc[t] = __builtin_amdgcn_mfma_f32_16x16x32_bf16(Ah1, Wl1, acc[t], 0, 0, 0);
      acc[t] = __builtin_amdgcn_mfma_f32_16x16x32_bf16(Al0, Wh0, acc[t], 0, 0, 0);
      acc[t] = __builtin_amdgcn_mfma_f32_16x16x32_bf16(Al1, Wh1, acc[t], 0, 0, 0);
    }
  }

#pragma unroll
  for (int t = 0; t < 4; ++t)
#pragma unroll
    for (int r = 0; r < 4; ++r) {
      const int key = t * 16 + quad * 4 + r;
      const int n = y * WW + key;
      const float v = acc[t][r];
      const unsigned short hi = f2h(v);               // fp16 hi
      const unsigned short lo = f2h(v - h2f(hi));     // fp16 lo
      fh[((size_t)b * NPIX + n) * CC + swzoff(n, og)] = hi;
      fl[((size_t)b * NPIX + n) * CC + swzoff(n, og)] = lo;
      fv[(((size_t)b * (NPIX >> 6) + y) * CC + og) * 64 + swzvslot(key, og)] =
          f2h(v);                                     // V^T fp16
    }
}

// ---------------------------------------------------------------------------
// pools: merged pool2 + pool4-direct (unchanged).
// ---------------------------------------------------------------------------
__global__ void pools_kernel(const unsigned short* __restrict__ in_h,
                             const unsigned short* __restrict__ in_l,
                             unsigned short* __restrict__ h2,
                             unsigned short* __restrict__ l2,
                             unsigned short* __restrict__ v2,
                             unsigned short* __restrict__ h4,
                             unsigned short* __restrict__ l4,
                             unsigned short* __restrict__ v4) {
  const int bid = blockIdx.x;
  if (bid < 2048) {           // ---- pool2: 64x64 -> 32x32 ----
    const int idx = bid * 256 + threadIdx.x;
    const int c  = idx & 63;
    const int t  = idx >> 6;
    const int xo = t & 31;
    const int yo = (t >> 5) & 31;
    const int b  = t >> 10;
    const size_t ibase = (size_t)b * NPIX * CC;
    float s = 0.f;
#pragma unroll
    for (int dy = 0; dy < 2; ++dy)
#pragma unroll
      for (int dx = 0; dx < 2; ++dx) {
        const int nin = (2*yo+dy) * 64 + (2*xo+dx);
        const size_t a = ibase + (size_t)nin * CC + swzoff(nin, c);
        s += h2f(in_h[a]) + h2f(in_l[a]);
      }
    const float vv = 0.25f * s;
    const unsigned short hi = f2h(vv);
    const int nout = yo * 32 + xo;
    const size_t ob = ((size_t)b * 1024 + nout) * CC + swzoff(nout, c);
    h2[ob] = hi;
    l2[ob] = f2h(vv - h2f(hi));
    v2[(((size_t)b * 16 + (nout >> 6)) * CC + c) * 64 + swzvslot(nout & 63, c)] =
        f2h(vv);
  } else {                    // ---- pool4: 64x64 -> 16x16 (direct) ----
    const int idx = (bid - 2048) * 256 + threadIdx.x;
    const int c  = idx & 63;
    const int t  = idx >> 6;
    const int xo = t & 15;
    const int yo = (t >> 4) & 15;
    const int b  = t >> 8;
    const size_t ibase = (size_t)b * NPIX * CC;
    float s = 0.f;
#pragma unroll
    for (int dy = 0; dy < 4; ++dy)
#pragma unroll
      for (int dx = 0; dx < 4; ++dx) {
        const int nin = (4*yo+dy) * 64 + (4*xo+dx);
        const size_t a = ibase + (size_t)nin * CC + swzoff(nin, c);
        s += h2f(in_h[a]) + h2f(in_l[a]);
      }
    const float vv = 0.0625f * s;
    const unsigned short hi = f2h(vv);
    const int nout = yo * 16 + xo;
    const size_t ob = ((size_t)b * 256 + nout) * CC + swzoff(nout, c);
    h4[ob] = hi;
    l4[ob] = f2h(vv - h2f(hi));
    v4[(((size_t)b * 4 + (nout >> 6)) * CC + c) * 64 + swzvslot(nout & 63, c)] =
        f2h(vv);
  }
}

// ---------------------------------------------------------------------------
// MFMA flash attention <NH, KS> — round-19 structure (S = Qh·Kh only);
// round 20: pk-cvt P pack + pointer-advance DMA addressing.
// round 21: -Mq folded into QK^T MFMA C-in.
// round 22: launch_bounds back to 4 (5 spilled O/Q to scratch).
// round 23/24: PV tt-pair K=32 merge with bounded live ranges + fence.
// round 25: V-DIRECT — V^T fragments read straight from global (L2-resident:
// each (b,ks) V slice is 128KB shared by 32 same-XCD blocks; staging it in
// LDS was pure overhead). KVT 32KB -> 16KB (K dbuf only) -> up to 8
// blocks/CU resident (launch_bounds(256,4) is a floor, not a cap).
// DMA per tile halves; barrier drains K only.
// ---------------------------------------------------------------------------
template <int NH, int KS>
__device__ __forceinline__ void attn_body(
    int bid,
    const unsigned short* __restrict__ fh,
    const unsigned short* __restrict__ fl,
    const unsigned short* __restrict__ fv,
    float* __restrict__ outF, unsigned short* __restrict__ outB,
    float* __restrict__ outL, int N,
    unsigned short* KVT) {
  const int tid  = threadIdx.x;
  const int lane = tid & 63;
  const int wave = tid >> 6;
  const int b    = bid & 7;              // XCD-local batch grouping
  const int rest = bid >> 3;
  const int nq   = N / (64 * NH);
  const int qt   = rest % nq;
  const int ks   = rest / nq;            // 0..KS-1
  const int q0   = qt * (64 * NH) + wave * (16 * NH);
  const int nt   = (N >> 6) / KS;
  const int t0   = ks * nt;
  const int r16  = lane & 15;
  const int quad = lane >> 4;
  const int swb  = r16 & 7;

  const unsigned short* fhB = fh + (size_t)b * N * CC;   // fp16 K/Q hi
  const unsigned short* flB = fl + (size_t)b * N * CC;   // fp16 Q lo
  const unsigned short* fvB = fv + (size_t)b * N * CC;   // fp16 tile-major V^T

  // ---- per-wave K DMA source pointers (advance by 4096 per tile) ----
  const unsigned short* gp[2];
  int ldsoff[2];
#pragma unroll
  for (int j = 0; j < 2; ++j) {
    const int cid = wave * 2 + j;        // 8 cids cover the 8KB K tile
    const int sub = cid << 9;            // shorts
    gp[j] = fhB + (size_t)t0 * 4096 + sub + lane * 8;
    ldsoff[j] = sub + lane * 8;
  }
  // ---- stage first K tile ----
#pragma unroll
  for (int j = 0; j < 2; ++j) {
    GLD_LDS16(gp[j], KVT + ldsoff[j]);
    gp[j] += 4096;
  }

  // ---- Q fragments per half: f = h+l (exact M), Qh = fp16(f*log2e) ----
  half8 Qh[NH][2];
  float Mq[NH];
#pragma unroll
  for (int h = 0; h < NH; ++h) {
    float Mpart = 0.f;
#pragma unroll
    for (int kss = 0; kss < 2; ++kss) {
      const size_t off = (size_t)(q0 + h * 16 + r16) * CC
                         + ((((kss << 2) + quad) ^ swb) << 3);
      const ushort8 hh = *(const ushort8*)(fhB + off);
      const ushort8 ll = *(const ushort8*)(flB + off);
      half8 sh;
#pragma unroll
      for (int j = 0; j < 8; ++j) {
        const float f = h2f(hh[j]) + h2f(ll[j]);
        const float g = f * LOG2E;
        sh[j] = (_Float16)g;
        Mpart += g * f;                  // = log2e * sum f^2 (partial)
      }
      Qh[h][kss] = sh;
    }
    Mpart += __shfl_xor(Mpart, 16, 64);
    Mpart += __shfl_xor(Mpart, 32, 64);  // M for q = r16, replicated
    Mq[h] = Mpart;                       // per-lane SCALAR (q = r16)
  }

  // ---- -Mq as an MFMA C-in fragment: QK^T lands pre-shifted ----
  floatx4 nMq[NH];
#pragma unroll
  for (int h = 0; h < NH; ++h)
    nMq[h] = (floatx4){-Mq[h], -Mq[h], -Mq[h], -Mq[h]};

  floatx4 O[NH][4];
  float lloc[NH];
#pragma unroll
  for (int h = 0; h < NH; ++h) {
    lloc[h] = 0.f;
#pragma unroll
    for (int ch = 0; ch < 4; ++ch) O[h][ch] = (floatx4){0.f, 0.f, 0.f, 0.f};
  }

  int koff[2];
#pragma unroll
  for (int kss = 0; kss < 2; ++kss) koff[kss] = (((kss << 2) + quad) ^ swb) << 3;

  for (int t = 0; t < nt; ++t) {
    const int cur = t & 1;
    __syncthreads();                    // drains K DMA for tile t, syncs block
    if (t + 1 < nt) {                   // issue K DMA for tile t+1 now
      unsigned short* dst = KVT + (cur ^ 1) * 4096;
#pragma unroll
      for (int j = 0; j < 2; ++j) {
        GLD_LDS16(gp[j], dst + ldsoff[j]);
        gp[j] += 4096;
      }
    }
    const unsigned short* kh = KVT + cur * 4096;            // fp16 K hi (LDS)
    const unsigned short* vtg = fvB + (size_t)(t0 + t) * 4096;  // V^T (global/L2)

#pragma unroll
    for (int tp = 0; tp < 2; ++tp) {    // tt-pair: keys [tp*32, tp*32+32)
      const int tt0 = tp * 2, tt1 = tp * 2 + 1;
      // ---- S^T for both halves; K fragments transient per scope ----
      floatx4 s0[NH], s1[NH];
      {
        const int kb = (tt0 * 16 + r16) * 64;
        const half8 Ka = *(const half8*)(kh + kb + koff[0]);
        const half8 Kb = *(const half8*)(kh + kb + koff[1]);
#pragma unroll
        for (int h = 0; h < NH; ++h) {
          s0[h] = __builtin_amdgcn_mfma_f32_16x16x32_f16(Ka, Qh[h][0], nMq[h], 0, 0, 0);
          s0[h] = __builtin_amdgcn_mfma_f32_16x16x32_f16(Kb, Qh[h][1], s0[h], 0, 0, 0);
        }
      }
      {
        const int kb = (tt1 * 16 + r16) * 64;
        const half8 Ka = *(const half8*)(kh + kb + koff[0]);
        const half8 Kb = *(const half8*)(kh + kb + koff[1]);
#pragma unroll
        for (int h = 0; h < NH; ++h) {
          s1[h] = __builtin_amdgcn_mfma_f32_16x16x32_f16(Ka, Qh[h][0], nMq[h], 0, 0, 0);
          s1[h] = __builtin_amdgcn_mfma_f32_16x16x32_f16(Kb, Qh[h][1], s1[h], 0, 0, 0);
        }
      }
      // ---- fixed-shift softmax + pack P pair into K=32 A-layout ----
      half8 Pf8[NH];
#pragma unroll
      for (int h = 0; h < NH; ++h) {
        const float p0 = __builtin_amdgcn_exp2f(s0[h][0]);
        const float p1 = __builtin_amdgcn_exp2f(s0[h][1]);
        const float p2 = __builtin_amdgcn_exp2f(s0[h][2]);
        const float p3 = __builtin_amdgcn_exp2f(s0[h][3]);
        const float p4 = __builtin_amdgcn_exp2f(s1[h][0]);
        const float p5 = __builtin_amdgcn_exp2f(s1[h][1]);
        const float p6 = __builtin_amdgcn_exp2f(s1[h][2]);
        const float p7 = __builtin_amdgcn_exp2f(s1[h][3]);
        lloc[h] += ((p0 + p1) + (p2 + p3)) + ((p4 + p5) + (p6 + p7));
        const auto a0 = __builtin_amdgcn_cvt_pkrtz(p0, p1);  // __fp16 x2
        const auto a1 = __builtin_amdgcn_cvt_pkrtz(p2, p3);
        const auto a2 = __builtin_amdgcn_cvt_pkrtz(p4, p5);
        const auto a3 = __builtin_amdgcn_cvt_pkrtz(p6, p7);
        Pf8[h] = (half8){(_Float16)a0[0], (_Float16)a0[1],
                         (_Float16)a1[0], (_Float16)a1[1],
                         (_Float16)a2[0], (_Float16)a2[1],
                         (_Float16)a3[0], (_Float16)a3[1]};
      }
      // Pressure fence: V loads + addressing may NOT hoist above this point.
      __builtin_amdgcn_sched_barrier(0);
      // ---- PV: per-ch V pair load (GLOBAL, L2-hot), consumed immediately ----
      const int vs0 = (((tt0 * 4 + quad) ^ r16) << 2);
      const int vs1 = (((tt1 * 4 + quad) ^ r16) << 2);
#pragma unroll
      for (int ch = 0; ch < 4; ++ch) {
        const half4 va = *(const half4*)(vtg + (ch * 16 + r16) * 64 + vs0);
        const half4 vb = *(const half4*)(vtg + (ch * 16 + r16) * 64 + vs1);
        const half8 Vf8 = (half8){va[0], va[1], va[2], va[3],
                                  vb[0], vb[1], vb[2], vb[3]};
#pragma unroll
        for (int h = 0; h < NH; ++h)
          O[h][ch] = __builtin_amdgcn_mfma_f32_16x16x32_f16(Pf8[h], Vf8,
                                                            O[h][ch], 0, 0, 0);
      }
    }
  }

  // ---- epilogue: l = reduce(lloc), spread to rows, store ----
#pragma unroll
  for (int h = 0; h < NH; ++h) {
    float lt = lloc[h];
    lt += __shfl_xor(lt, 16, 64);
    lt += __shfl_xor(lt, 32, 64);       // l for q = r16, replicated
    float lq[4];
#pragma unroll
    for (int r = 0; r < 4; ++r) lq[r] = __shfl(lt, quad * 4 + r, 16);
    if (KS != 1 && r16 == 0) {
#pragma unroll
      for (int r = 0; r < 4; ++r)
        outL[(size_t)ks * BB * N + (size_t)b * N + q0 + h * 16 + quad * 4 + r] =
            lq[r];
    }
#pragma unroll
    for (int ch = 0; ch < 4; ++ch)
#pragma unroll
      for (int r = 0; r < 4; ++r) {
        const size_t qi = (size_t)b * N + q0 + h * 16 + quad * 4 + r;
        if (KS == 1) {
          outF[qi * CC + ch * 16 + r16] = O[h][ch][r] / lq[r];
        } else {
          outB[(size_t)ks * BB * N * CC + qi * CC + ch * 16 + r16] =
              f2bf_fast(O[h][ch][r]);
        }
      }
  }
}

// Merged dispatch — short blocks first (tail-fill), segment offsets ≡0 mod 8
// so b = bid&7 XCD grouping is preserved.
// [0,256) scale-2 NH=1/KS=2; [256,288) scale-4 NH=1/KS=1;
// [288,1312) scale-1 NH=2/KS=4. LDS 16KB (K dbuf only) -> up to 8 blocks/CU.
__global__ __launch_bounds__(256, 4) void attn_all(
    const unsigned short* __restrict__ fh1, const unsigned short* __restrict__ fl1,
    const unsigned short* __restrict__ fv1,
    unsigned short* __restrict__ Op1, float* __restrict__ Lp1,
    const unsigned short* __restrict__ fh2, const unsigned short* __restrict__ fl2,
    const unsigned short* __restrict__ fv2,
    unsigned short* __restrict__ Op2, float* __restrict__ Lp2,
    const unsigned short* __restrict__ fh4, const unsigned short* __restrict__ fl4,
    const unsigned short* __restrict__ fv4, float* __restrict__ a4) {
  __shared__ __align__(16) unsigned short KVT[2][4096];   // 16KB K dbuf
  const int bid = blockIdx.x;
  if (bid < 256) {
    attn_body<1, 2>(bid, fh2, fl2, fv2, nullptr, Op2, Lp2, 1024, &KVT[0][0]);
  } else if (bid < 288) {
    attn_body<1, 1>(bid - 256, fh4, fl4, fv4, a4, nullptr, nullptr, 256,
                    &KVT[0][0]);
  } else {
    attn_body<2, 4>(bid - 288, fh1, fl1, fv1, nullptr, Op1, Lp1, NPIX,
                    &KVT[0][0]);
  }
}

// ---------------------------------------------------------------------------
// final3: FUSED scale-1 combine (4 partials) + scale-2 combine (2 partials)
// + output assembly. Block = (b, y-row). (unchanged)
// ---------------------------------------------------------------------------
__global__ __launch_bounds__(256) void final3_kernel(
    const float* __restrict__ xin,
    const unsigned short* __restrict__ Op1, const float* __restrict__ Lp1,
    const unsigned short* __restrict__ Op2, const float* __restrict__ Lp2,
    const float* __restrict__ a4, float* __restrict__ out) {
  __shared__ float T[64][65];
  __shared__ float T2[64][66];
  const int tid = threadIdx.x;
  const int y = blockIdx.x & 63;
  const int b = blockIdx.x >> 6;
  const size_t S1 = (size_t)BB * NPIX * CC;
  const size_t T1 = (size_t)BB * NPIX;
  const size_t S2 = (size_t)BB * 1024 * CC;
  const size_t L2 = (size_t)BB * 1024;

  const float ty2 = y * 0.5f - 0.25f;
  const int iy2 = (int)floorf(ty2);
  const float wy2 = ty2 - iy2;
  const int iy20 = max(iy2, 0), iy21 = min(iy2 + 1, 31);

  const int nl = tid >> 2;             // 0..63
  const int ck = (tid & 3) * 16;       // c chunk

  {  // ---- phase 1: combine scale-1 row y (4 partials) ----
    const int n = y * 64 + nl;
    float lv = 0.f;
#pragma unroll
    for (int ks = 0; ks < 4; ++ks)
      lv += Lp1[(size_t)ks * T1 + (size_t)b * NPIX + n];
    const float inv = 1.f / lv;
    float v[16];
#pragma unroll
    for (int j = 0; j < 16; ++j) v[j] = 0.f;
#pragma unroll
    for (int ks = 0; ks < 4; ++ks) {
      const unsigned short* src =
          Op1 + (size_t)ks * S1 + ((size_t)b * NPIX + n) * CC + ck;
      const ushort8 u0 = *(const ushort8*)(src);
      const ushort8 u1 = *(const ushort8*)(src + 8);
#pragma unroll
      for (int j = 0; j < 8; ++j) {
        v[j]     += bf2f(u0[j]);
        v[8 + j] += bf2f(u1[j]);
      }
    }
#pragma unroll
    for (int j = 0; j < 16; ++j) T[ck + j][nl] = v[j] * inv;
  }
  {  // ---- phase 1b: combine scale-2 rows iy20 (nl<32) / iy21 (nl>=32) ----
    const int row = nl >> 5;
    const int ix  = nl & 31;
    const int n2  = (row == 0 ? iy20 : iy21) * 32 + ix;
    float lv = Lp2[(size_t)b * 1024 + n2] + Lp2[L2 + (size_t)b * 1024 + n2];
    const float inv = 1.f / lv;
    float v[16];
#pragma unroll
    for (int j = 0; j < 16; ++j) v[j] = 0.f;
#pragma unroll
    for (int ks = 0; ks < 2; ++ks) {
      const unsigned short* src =
          Op2 + (size_t)ks * S2 + ((size_t)b * 1024 + n2) * CC + ck;
      const ushort8 u0 = *(const ushort8*)(src);
      const ushort8 u1 = *(const ushort8*)(src + 8);
#pragma unroll
      for (int j = 0; j < 8; ++j) {
        v[j]     += bf2f(u0[j]);
        v[8 + j] += bf2f(u1[j]);
      }
    }
#pragma unroll
    for (int j = 0; j < 16; ++j) T2[ck + j][nl] = v[j] * inv;
  }
  __syncthreads();

  // ---- phase 2: assemble output row ----
  const int c  = tid >> 2;
  const int xk = (tid & 3) * 16;
  const float* xrow = xin + (((size_t)b * CC + c) * HH + y) * WW;
  float* orow = out + (((size_t)b * CC + c) * HH + y) * WW;

  const float ty4 = y * 0.25f - 0.375f;
  const int iy4 = (int)floorf(ty4);
  const float wy4 = ty4 - iy4;
  const int iy40 = max(iy4, 0), iy41 = min(iy4 + 1, 15);
  const float* b4 = a4 + (size_t)b * 256 * 64 + c;

#pragma unroll
  for (int j = 0; j < 16; ++j) {
    const int xx = xk + j;
    float r = xrow[xx] + T[c][xx];
    {  // scale 2 (rows pre-combined in T2: cols 0-31 = iy20, 32-63 = iy21)
      const float tx = xx * 0.5f - 0.25f;
      const int ix = (int)floorf(tx);
      const float wx = tx - ix;
      const int ix0 = max(ix, 0), ix1 = min(ix + 1, 31);
      const float v00 = T2[c][ix0],      v01 = T2[c][ix1];
      const float v10 = T2[c][32 + ix0], v11 = T2[c][32 + ix1];
      r += (1.f-wy2)*((1.f-wx)*v00 + wx*v01) + wy2*((1.f-wx)*v10 + wx*v11);
    }
    {  // scale 4
      const float tx = xx * 0.25f - 0.375f;
      const int ix = (int)floorf(tx);
      const float wx = tx - ix;
      const int ix0 = max(ix, 0), ix1 = min(ix + 1, 15);
      const float v00 = b4[(iy40*16+ix0)*64], v01 = b4[(iy40*16+ix1)*64];
      const float v10 = b4[(iy41*16+ix0)*64], v11 = b4[(iy41*16+ix1)*64];
      r += (1.f-wy4)*((1.f-wx)*v00 + wx*v01) + wy4*((1.f-wx)*v10 + wx*v11);
    }
    orow[xx] = r;
  }
}

// ---------------------------------------------------------------------------
extern "C" void kernel_launch(void* const* d_in, const int* in_sizes, int n_in,
                              void* d_out, int out_size, void* d_ws,
                              size_t ws_size, hipStream_t stream) {
  const float* x = (const float*)d_in[0];
  const float* w = (const float*)d_in[1];
  float* out = (float*)d_out;

  unsigned short* fh1 = (unsigned short*)d_ws;            // [8][4096][64] fp16 swz
  unsigned short* fl1 = fh1 + (size_t)BB*NPIX*CC;         // fp16 lo
  unsigned short* fv1 = fl1 + (size_t)BB*NPIX*CC;         // fp16 tile-major V^T
  unsigned short* fh2 = fv1 + (size_t)BB*NPIX*CC;         // [8][1024][64]
  unsigned short* fl2 = fh2 + (size_t)BB*1024*CC;
  unsigned short* fv2 = fl2 + (size_t)BB*1024*CC;
  unsigned short* fh4 = fv2 + (size_t)BB*1024*CC;         // [8][256][64]
  unsigned short* fl4 = fh4 + (size_t)BB*256*CC;
  unsigned short* fv4 = fl4 + (size_t)BB*256*CC;
  unsigned short* Op1 = fv4 + (size_t)BB*256*CC;          // [4][8][4096][64] bf16
  float* Lp1 = (float*)(Op1 + 4*(size_t)BB*NPIX*CC);      // [4][8][4096]
  unsigned short* Op2 = (unsigned short*)(Lp1 + 4*(size_t)BB*NPIX);  // [2][8][1024][64]
  float* Lp2 = (float*)(Op2 + 2*(size_t)BB*1024*CC);      // [2][8][1024]
  float* a4  = Lp2 + 2*(size_t)BB*1024;                   // [8][256][64] fp32

  // Dead-time aliases: WT (dead after conv_mfma) aliases Op2 (attn later)
  unsigned short* wth = (unsigned short*)Op2;             // 72 KB
  unsigned short* wtl = wth + 9*64*64;                    // 72 KB

  wprep_kernel<<<144, 256, 0, stream>>>(w, wth, wtl);
  conv_mfma<<<dim3(64, 8), 256, 0, stream>>>(x, wth, wtl, fh1, fl1, fv1);
  pools_kernel<<<2560, 256, 0, stream>>>(fh1, fl1, fh2, fl2, fv2, fh4, fl4, fv4);
  attn_all<<<1312, 256, 0, stream>>>(fh1, fl1, fv1, Op1, Lp1,
                                     fh2, fl2, fv2, Op2, Lp2,
                                     fh4, fl4, fv4, a4);
  final3_kernel<<<512, 256, 0, stream>>>(x, Op1, Lp1, Op2, Lp2, a4, out);
}

// Round 6
// 163.898 us; speedup vs baseline: 1.0876x; 1.0876x over previous
//
#include <hip/hip_runtime.h>
#include <hip/hip_bf16.h>
#include <math.h>

// Problem constants: x [8,64,64,64] fp32 NCHW, W_std [64,64,3,3] fp32 OIHW.
#define BB 8
#define CC 64
#define HH 64
#define WW 64
#define NPIX (HH*WW)   // 4096
#define LOG2E 1.44269504088896340736f

typedef __attribute__((ext_vector_type(8))) short bf16x8;            // bf16 A/B frag
typedef __attribute__((ext_vector_type(8))) _Float16 half8;          // fp16 A/B frag (K=32)
typedef __attribute__((ext_vector_type(4))) _Float16 half4;          // fp16 A/B frag (K=16)
typedef __attribute__((ext_vector_type(4))) float floatx4;           // MFMA C/D frag
typedef __attribute__((ext_vector_type(8))) unsigned short ushort8;  // 16B unit

__device__ inline unsigned short f2bf(float x) {
  __hip_bfloat16 h = __float2bfloat16(x);
  return *reinterpret_cast<unsigned short*>(&h);
}
__device__ inline unsigned short f2bf_fast(float x) {
  const unsigned u = __float_as_uint(x);
  return (unsigned short)((u + 0x8000u) >> 16);
}
__device__ inline float bf2f(unsigned short u) {
  __hip_bfloat16 h = *reinterpret_cast<__hip_bfloat16*>(&u);
  return __bfloat162float(h);
}
__device__ inline unsigned short f2h(float x) {
  _Float16 h = (_Float16)x;
  return *reinterpret_cast<unsigned short*>(&h);
}
__device__ inline float h2f(unsigned short u) {
  _Float16 h = *reinterpret_cast<_Float16*>(&u);
  return (float)h;
}

// XOR swizzle for K/Q rows: 16B chunks permuted within each 128B row.
__device__ inline int swzoff(int n, int c) {
  return (((c >> 3) ^ (n & 7)) << 3) | (c & 7);
}
// V^T swizzle: b64-granular (round 18 — measured 4.75M -> 0 conflicts).
__device__ inline int swzvslot(int key, int c) {
  return ((((key >> 2) ^ (c & 15)) << 2)) | (key & 3);
}

// 16B global -> LDS DMA (per-lane global scatter OK; LDS dest = base+lane*16)
#define GLD_LDS16(gp, lp)                                                     \
  __builtin_amdgcn_global_load_lds(                                           \
      (const __attribute__((address_space(1))) void*)(gp),                    \
      (__attribute__((address_space(3))) void*)(lp), 16, 0, 0)

// ---------------------------------------------------------------------------
// wprep: WT[tap][o][c] bf16 hi/lo, depthwise Laplacian folded in.
// ---------------------------------------------------------------------------
__global__ __launch_bounds__(256) void wprep_kernel(
    const float* __restrict__ w,
    unsigned short* __restrict__ wth, unsigned short* __restrict__ wtl) {
  const int idx = blockIdx.x * 256 + threadIdx.x;   // 9*64*64 = 36864
  const int c   = idx & 63;
  const int o   = (idx >> 6) & 63;
  const int tap = idx >> 12;
  float v = w[((o * 64 + c) * 9) + tap];
  if (o == c) {
    const float lapk[9] = {0.f, 1.f, 0.f, 1.f, -4.f, 1.f, 0.f, 1.f, 0.f};
    v += lapk[tap];
  }
  const unsigned short hi = f2bf(v);
  wth[(tap * 64 + o) * 64 + c] = hi;
  wtl[(tap * 64 + o) * 64 + c] = f2bf(v - bf2f(hi));
}

// ---------------------------------------------------------------------------
// conv_mfma: implicit-GEMM conv. Round 20: SINGLE-PHASE staging — DMA all
// 3 fp32 x-rows (48KB) into the XS region itself, drain ONCE, copy each
// thread's 48 values to registers, barrier, convert/write the swizzled
// bf16 hi/lo layout in place. 6 barriers -> 3, XLf gone, LDS 64 -> 48KB
// -> 3 blocks/CU.
// ---------------------------------------------------------------------------
__global__ __launch_bounds__(256, 3) void conv_mfma(
    const float* __restrict__ xin,
    const unsigned short* __restrict__ wth,
    const unsigned short* __restrict__ wtl,
    unsigned short* __restrict__ fh, unsigned short* __restrict__ fl,
    unsigned short* __restrict__ fv) {
  __shared__ __align__(16) unsigned short XS[6 * 4096];  // 48KB

  const int tid  = threadIdx.x;
  const int lane = tid & 63;
  const int wave = tid >> 6;
  const int r16  = lane & 15;
  const int quad = lane >> 4;
  const int y = blockIdx.x, b = blockIdx.y;
  const int px = tid & 63, cp = tid >> 6;

  // ---- stage: DMA 3 rows fp32 [c][x] into XS bytes [r*16KB ...] ----
  float* XSf = (float*)XS;
  const float* xb = xin + (size_t)b * CC * NPIX;
#pragma unroll
  for (int r = 0; r < 3; ++r) {
    const int yy = min(max(y - 1 + r, 0), HH - 1);
    const float* xrow = xb + yy * WW;
#pragma unroll
    for (int j = 0; j < 4; ++j) {
      const int cb = (wave * 4 + j) * 4;        // 4 channel-rows per DMA
      const int cl = cb + (lane >> 4);
      const float* g = xrow + (size_t)cl * NPIX + ((lane & 15) << 2);
      GLD_LDS16(g, (char*)XSf + r * 16384 + cb * 256 + lane * 16);
    }
  }
  __syncthreads();                              // single DMA drain

  // ---- copy this thread's 48 values to regs (fp32 region dies next) ----
  float xv[3][16];
#pragma unroll
  for (int r = 0; r < 3; ++r)
#pragma unroll
    for (int j = 0; j < 16; ++j)
      xv[r][j] = XSf[r * 4096 + (cp * 16 + j) * 64 + px];
  __syncthreads();                              // all reads done

  // ---- convert/write swizzled bf16 hi/lo in place ----
#pragma unroll
  for (int r = 0; r < 3; ++r) {
    ushort8 vh[2], vl[2];
#pragma unroll
    for (int j = 0; j < 16; ++j) {
      const float v = xv[r][j];
      const unsigned short hh = f2bf(v);
      vh[j >> 3][j & 7] = hh;
      vl[j >> 3][j & 7] = f2bf(v - bf2f(hh));
    }
    unsigned short* xsh = XS + r * 4096 + px * 64;
    unsigned short* xsl = XS + (3 + r) * 4096 + px * 64;
#pragma unroll
    for (int k = 0; k < 2; ++k) {
      const int ch = cp * 2 + k;
      const int off = ((ch ^ (px & 7)) << 3);
      *(ushort8*)(xsh + off) = vh[k];
      *(ushort8*)(xsl + off) = vl[k];
    }
  }
  __syncthreads();                              // XS ready

  floatx4 acc[4];
#pragma unroll
  for (int t = 0; t < 4; ++t) acc[t] = (floatx4){0.f, 0.f, 0.f, 0.f};
  const bf16x8 ZF = {0, 0, 0, 0, 0, 0, 0, 0};
  const int og = wave * 16 + r16;

#pragma unroll
  for (int tap = 0; tap < 9; ++tap) {
    const int ky = tap / 3, kx = tap % 3;
    const int yy = y + ky - 1;
    if (yy < 0 || yy >= HH) continue;
    const unsigned short* wt = wth + ((tap * 64 + og) << 6);
    const unsigned short* wl = wtl + ((tap * 64 + og) << 6);
    const bf16x8 Wh0 = *(const bf16x8*)(wt + quad * 8);
    const bf16x8 Wh1 = *(const bf16x8*)(wt + 32 + quad * 8);
    const bf16x8 Wl0 = *(const bf16x8*)(wl + quad * 8);
    const bf16x8 Wl1 = *(const bf16x8*)(wl + 32 + quad * 8);
#pragma unroll
    for (int t = 0; t < 4; ++t) {
      const int px2 = t * 16 + r16 + kx - 1;
      const bool ok = (px2 >= 0) && (px2 < WW);
      const int pxc = ok ? px2 : 0;
      const int bh = ky * 4096 + pxc * 64;
      const int bl = bh + 3 * 4096;
      const int o0 = ((quad ^ (pxc & 7)) << 3);
      const int o1 = (((4 + quad) ^ (pxc & 7)) << 3);
      bf16x8 Ah0 = *(const bf16x8*)(XS + bh + o0);
      bf16x8 Ah1 = *(const bf16x8*)(XS + bh + o1);
      bf16x8 Al0 = *(const bf16x8*)(XS + bl + o0);
      bf16x8 Al1 = *(const bf16x8*)(XS + bl + o1);
      if (!ok) { Ah0 = ZF; Ah1 = ZF; Al0 = ZF; Al1 = ZF; }
      acc[t] = __builtin_amdgcn_mfma_f32_16x16x32_bf16(Ah0, Wh0, acc[t], 0, 0, 0);
      acc[t] = __builtin_amdgcn_mfma_f32_16x16x32_bf16(Ah1, Wh1, acc[t], 0, 0, 0);
      acc[t] = __builtin_amdgcn_mfma_f32_16x16x32_bf16(Ah0, Wl0, acc[t], 0, 0, 0);
      acc[t] = __builtin_amdgcn_mfma_f32_16x16x32_bf16(Ah1, Wl1, acc[t], 0, 0, 0);
      acc[t] = __builtin_amdgcn_mfma_f32_16x16x32_bf16(Al0, Wh0, acc[t], 0, 0, 0);
      acc[t] = __builtin_amdgcn_mfma_f32_16x16x32_bf16(Al1, Wh1, acc[t], 0, 0, 0);
    }
  }

#pragma unroll
  for (int t = 0; t < 4; ++t)
#pragma unroll
    for (int r = 0; r < 4; ++r) {
      const int key = t * 16 + quad * 4 + r;
      const int n = y * WW + key;
      const float v = acc[t][r];
      const unsigned short hi = f2h(v);               // fp16 hi
      const unsigned short lo = f2h(v - h2f(hi));     // fp16 lo
      fh[((size_t)b * NPIX + n) * CC + swzoff(n, og)] = hi;
      fl[((size_t)b * NPIX + n) * CC + swzoff(n, og)] = lo;
      fv[(((size_t)b * (NPIX >> 6) + y) * CC + og) * 64 + swzvslot(key, og)] =
          f2h(v);                                     // V^T fp16
    }
}

// ---------------------------------------------------------------------------
// pools: merged pool2 + pool4-direct (unchanged).
// ---------------------------------------------------------------------------
__global__ void pools_kernel(const unsigned short* __restrict__ in_h,
                             const unsigned short* __restrict__ in_l,
                             unsigned short* __restrict__ h2,
                             unsigned short* __restrict__ l2,
                             unsigned short* __restrict__ v2,
                             unsigned short* __restrict__ h4,
                             unsigned short* __restrict__ l4,
                             unsigned short* __restrict__ v4) {
  const int bid = blockIdx.x;
  if (bid < 2048) {           // ---- pool2: 64x64 -> 32x32 ----
    const int idx = bid * 256 + threadIdx.x;
    const int c  = idx & 63;
    const int t  = idx >> 6;
    const int xo = t & 31;
    const int yo = (t >> 5) & 31;
    const int b  = t >> 10;
    const size_t ibase = (size_t)b * NPIX * CC;
    float s = 0.f;
#pragma unroll
    for (int dy = 0; dy < 2; ++dy)
#pragma unroll
      for (int dx = 0; dx < 2; ++dx) {
        const int nin = (2*yo+dy) * 64 + (2*xo+dx);
        const size_t a = ibase + (size_t)nin * CC + swzoff(nin, c);
        s += h2f(in_h[a]) + h2f(in_l[a]);
      }
    const float vv = 0.25f * s;
    const unsigned short hi = f2h(vv);
    const int nout = yo * 32 + xo;
    const size_t ob = ((size_t)b * 1024 + nout) * CC + swzoff(nout, c);
    h2[ob] = hi;
    l2[ob] = f2h(vv - h2f(hi));
    v2[(((size_t)b * 16 + (nout >> 6)) * CC + c) * 64 + swzvslot(nout & 63, c)] =
        f2h(vv);
  } else {                    // ---- pool4: 64x64 -> 16x16 (direct) ----
    const int idx = (bid - 2048) * 256 + threadIdx.x;
    const int c  = idx & 63;
    const int t  = idx >> 6;
    const int xo = t & 15;
    const int yo = (t >> 4) & 15;
    const int b  = t >> 8;
    const size_t ibase = (size_t)b * NPIX * CC;
    float s = 0.f;
#pragma unroll
    for (int dy = 0; dy < 4; ++dy)
#pragma unroll
      for (int dx = 0; dx < 4; ++dx) {
        const int nin = (4*yo+dy) * 64 + (4*xo+dx);
        const size_t a = ibase + (size_t)nin * CC + swzoff(nin, c);
        s += h2f(in_h[a]) + h2f(in_l[a]);
      }
    const float vv = 0.0625f * s;
    const unsigned short hi = f2h(vv);
    const int nout = yo * 16 + xo;
    const size_t ob = ((size_t)b * 256 + nout) * CC + swzoff(nout, c);
    h4[ob] = hi;
    l4[ob] = f2h(vv - h2f(hi));
    v4[(((size_t)b * 4 + (nout >> 6)) * CC + c) * 64 + swzvslot(nout & 63, c)] =
        f2h(vv);
  }
}

// ---------------------------------------------------------------------------
// MFMA flash attention <NH, KS> — round-19 structure (S = Qh·Kh only);
// round 20: pk-cvt P pack + pointer-advance DMA addressing.
// round 21: -Mq folded into QK^T MFMA C-in.
// round 22: launch_bounds back to 4 (5 spilled O/Q to scratch).
// round 23/24: PV tt-pair K=32 merge with bounded live ranges + fence.
// round 25: V-direct-from-global — REVERTED (attn 48->88us: unhideable L2
// gather latency behind the fence + L2 churn doubled HBM write traffic).
// round 26: back to round-24 structure (V staged in LDS, 32KB) +
// s_setprio(1) around the MFMA clusters (T5: co-resident blocks sit at
// different tile-loop phases -> priority arbitration has role diversity).
// ---------------------------------------------------------------------------
template <int NH, int KS>
__device__ __forceinline__ void attn_body(
    int bid,
    const unsigned short* __restrict__ fh,
    const unsigned short* __restrict__ fl,
    const unsigned short* __restrict__ fv,
    float* __restrict__ outF, unsigned short* __restrict__ outB,
    float* __restrict__ outL, int N,
    unsigned short* KVT) {
  const int tid  = threadIdx.x;
  const int lane = tid & 63;
  const int wave = tid >> 6;
  const int b    = bid & 7;              // XCD-local batch grouping
  const int rest = bid >> 3;
  const int nq   = N / (64 * NH);
  const int qt   = rest % nq;
  const int ks   = rest / nq;            // 0..KS-1
  const int q0   = qt * (64 * NH) + wave * (16 * NH);
  const int nt   = (N >> 6) / KS;
  const int t0   = ks * nt;
  const int r16  = lane & 15;
  const int quad = lane >> 4;
  const int swb  = r16 & 7;

  const unsigned short* fhB = fh + (size_t)b * N * CC;   // fp16 K/Q hi
  const unsigned short* flB = fl + (size_t)b * N * CC;   // fp16 Q lo
  const unsigned short* fvB = fv + (size_t)b * N * CC;   // fp16 tile-major V^T

  // ---- per-wave DMA source pointers (advance by 4096 per tile) ----
  const unsigned short* gp[4];
  int ldsoff[4];
#pragma unroll
  for (int j = 0; j < 4; ++j) {
    const int cid = wave * 4 + j;
    const int arr = cid >> 3, sub = (cid & 7) << 9;
    gp[j] = (arr == 0 ? fhB : fvB) + (size_t)t0 * 4096 + sub + lane * 8;
    ldsoff[j] = arr * 4096 + sub + lane * 8;
  }
  // ---- stage first tile ----
#pragma unroll
  for (int j = 0; j < 4; ++j) {
    GLD_LDS16(gp[j], KVT + ldsoff[j]);
    gp[j] += 4096;
  }

  // ---- Q fragments per half: f = h+l (exact M), Qh = fp16(f*log2e) ----
  half8 Qh[NH][2];
  float Mq[NH];
#pragma unroll
  for (int h = 0; h < NH; ++h) {
    float Mpart = 0.f;
#pragma unroll
    for (int kss = 0; kss < 2; ++kss) {
      const size_t off = (size_t)(q0 + h * 16 + r16) * CC
                         + ((((kss << 2) + quad) ^ swb) << 3);
      const ushort8 hh = *(const ushort8*)(fhB + off);
      const ushort8 ll = *(const ushort8*)(flB + off);
      half8 sh;
#pragma unroll
      for (int j = 0; j < 8; ++j) {
        const float f = h2f(hh[j]) + h2f(ll[j]);
        const float g = f * LOG2E;
        sh[j] = (_Float16)g;
        Mpart += g * f;                  // = log2e * sum f^2 (partial)
      }
      Qh[h][kss] = sh;
    }
    Mpart += __shfl_xor(Mpart, 16, 64);
    Mpart += __shfl_xor(Mpart, 32, 64);  // M for q = r16, replicated
    Mq[h] = Mpart;                       // per-lane SCALAR (q = r16)
  }

  // ---- -Mq as an MFMA C-in fragment: QK^T lands pre-shifted ----
  floatx4 nMq[NH];
#pragma unroll
  for (int h = 0; h < NH; ++h)
    nMq[h] = (floatx4){-Mq[h], -Mq[h], -Mq[h], -Mq[h]};

  floatx4 O[NH][4];
  float lloc[NH];
#pragma unroll
  for (int h = 0; h < NH; ++h) {
    lloc[h] = 0.f;
#pragma unroll
    for (int ch = 0; ch < 4; ++ch) O[h][ch] = (floatx4){0.f, 0.f, 0.f, 0.f};
  }

  int koff[2];
#pragma unroll
  for (int kss = 0; kss < 2; ++kss) koff[kss] = (((kss << 2) + quad) ^ swb) << 3;

  for (int t = 0; t < nt; ++t) {
    const int cur = t & 1;
    __syncthreads();                    // drains DMA for tile t, syncs block
    if (t + 1 < nt) {                   // issue DMA for tile t+1 now
      unsigned short* dst = KVT + (cur ^ 1) * 8192;
#pragma unroll
      for (int j = 0; j < 4; ++j) {
        GLD_LDS16(gp[j], dst + ldsoff[j]);
        gp[j] += 4096;
      }
    }
    const unsigned short* kh = KVT + cur * 8192;   // fp16 K hi
    const unsigned short* vt = kh + 4096;          // fp16 V^T

#pragma unroll
    for (int tp = 0; tp < 2; ++tp) {    // tt-pair: keys [tp*32, tp*32+32)
      const int tt0 = tp * 2, tt1 = tp * 2 + 1;
      // ---- S^T for both halves; K fragments transient per scope ----
      floatx4 s0[NH], s1[NH];
      __builtin_amdgcn_s_setprio(1);
      {
        const int kb = (tt0 * 16 + r16) * 64;
        const half8 Ka = *(const half8*)(kh + kb + koff[0]);
        const half8 Kb = *(const half8*)(kh + kb + koff[1]);
#pragma unroll
        for (int h = 0; h < NH; ++h) {
          s0[h] = __builtin_amdgcn_mfma_f32_16x16x32_f16(Ka, Qh[h][0], nMq[h], 0, 0, 0);
          s0[h] = __builtin_amdgcn_mfma_f32_16x16x32_f16(Kb, Qh[h][1], s0[h], 0, 0, 0);
        }
      }
      {
        const int kb = (tt1 * 16 + r16) * 64;
        const half8 Ka = *(const half8*)(kh + kb + koff[0]);
        const half8 Kb = *(const half8*)(kh + kb + koff[1]);
#pragma unroll
        for (int h = 0; h < NH; ++h) {
          s1[h] = __builtin_amdgcn_mfma_f32_16x16x32_f16(Ka, Qh[h][0], nMq[h], 0, 0, 0);
          s1[h] = __builtin_amdgcn_mfma_f32_16x16x32_f16(Kb, Qh[h][1], s1[h], 0, 0, 0);
        }
      }
      __builtin_amdgcn_s_setprio(0);
      // ---- fixed-shift softmax + pack P pair into K=32 A-layout ----
      half8 Pf8[NH];
#pragma unroll
      for (int h = 0; h < NH; ++h) {
        const float p0 = __builtin_amdgcn_exp2f(s0[h][0]);
        const float p1 = __builtin_amdgcn_exp2f(s0[h][1]);
        const float p2 = __builtin_amdgcn_exp2f(s0[h][2]);
        const float p3 = __builtin_amdgcn_exp2f(s0[h][3]);
        const float p4 = __builtin_amdgcn_exp2f(s1[h][0]);
        const float p5 = __builtin_amdgcn_exp2f(s1[h][1]);
        const float p6 = __builtin_amdgcn_exp2f(s1[h][2]);
        const float p7 = __builtin_amdgcn_exp2f(s1[h][3]);
        lloc[h] += ((p0 + p1) + (p2 + p3)) + ((p4 + p5) + (p6 + p7));
        const auto a0 = __builtin_amdgcn_cvt_pkrtz(p0, p1);  // __fp16 x2
        const auto a1 = __builtin_amdgcn_cvt_pkrtz(p2, p3);
        const auto a2 = __builtin_amdgcn_cvt_pkrtz(p4, p5);
        const auto a3 = __builtin_amdgcn_cvt_pkrtz(p6, p7);
        Pf8[h] = (half8){(_Float16)a0[0], (_Float16)a0[1],
                         (_Float16)a1[0], (_Float16)a1[1],
                         (_Float16)a2[0], (_Float16)a2[1],
                         (_Float16)a3[0], (_Float16)a3[1]};
      }
      // Pressure fence: V loads + addressing may NOT hoist above this point.
      __builtin_amdgcn_sched_barrier(0);
      // ---- PV: per-ch V pair load, consumed immediately ----
      const int vs0 = (((tt0 * 4 + quad) ^ r16) << 2);
      const int vs1 = (((tt1 * 4 + quad) ^ r16) << 2);
      __builtin_amdgcn_s_setprio(1);
#pragma unroll
      for (int ch = 0; ch < 4; ++ch) {
        const half4 va = *(const half4*)(vt + (ch * 16 + r16) * 64 + vs0);
        const half4 vb = *(const half4*)(vt + (ch * 16 + r16) * 64 + vs1);
        const half8 Vf8 = (half8){va[0], va[1], va[2], va[3],
                                  vb[0], vb[1], vb[2], vb[3]};
#pragma unroll
        for (int h = 0; h < NH; ++h)
          O[h][ch] = __builtin_amdgcn_mfma_f32_16x16x32_f16(Pf8[h], Vf8,
                                                            O[h][ch], 0, 0, 0);
      }
      __builtin_amdgcn_s_setprio(0);
    }
  }

  // ---- epilogue: l = reduce(lloc), spread to rows, store ----
#pragma unroll
  for (int h = 0; h < NH; ++h) {
    float lt = lloc[h];
    lt += __shfl_xor(lt, 16, 64);
    lt += __shfl_xor(lt, 32, 64);       // l for q = r16, replicated
    float lq[4];
#pragma unroll
    for (int r = 0; r < 4; ++r) lq[r] = __shfl(lt, quad * 4 + r, 16);
    if (KS != 1 && r16 == 0) {
#pragma unroll
      for (int r = 0; r < 4; ++r)
        outL[(size_t)ks * BB * N + (size_t)b * N + q0 + h * 16 + quad * 4 + r] =
            lq[r];
    }
#pragma unroll
    for (int ch = 0; ch < 4; ++ch)
#pragma unroll
      for (int r = 0; r < 4; ++r) {
        const size_t qi = (size_t)b * N + q0 + h * 16 + quad * 4 + r;
        if (KS == 1) {
          outF[qi * CC + ch * 16 + r16] = O[h][ch][r] / lq[r];
        } else {
          outB[(size_t)ks * BB * N * CC + qi * CC + ch * 16 + r16] =
              f2bf_fast(O[h][ch][r]);
        }
      }
  }
}

// Merged dispatch — short blocks first (tail-fill), segment offsets ≡0 mod 8
// so b = bid&7 XCD grouping is preserved.
// [0,256) scale-2 NH=1/KS=2; [256,288) scale-4 NH=1/KS=1;
// [288,1312) scale-1 NH=2/KS=4. LDS 32KB -> 4 blocks/CU (VGPR cap 128).
__global__ __launch_bounds__(256, 4) void attn_all(
    const unsigned short* __restrict__ fh1, const unsigned short* __restrict__ fl1,
    const unsigned short* __restrict__ fv1,
    unsigned short* __restrict__ Op1, float* __restrict__ Lp1,
    const unsigned short* __restrict__ fh2, const unsigned short* __restrict__ fl2,
    const unsigned short* __restrict__ fv2,
    unsigned short* __restrict__ Op2, float* __restrict__ Lp2,
    const unsigned short* __restrict__ fh4, const unsigned short* __restrict__ fl4,
    const unsigned short* __restrict__ fv4, float* __restrict__ a4) {
  __shared__ __align__(16) unsigned short KVT[2][2 * 4096];
  const int bid = blockIdx.x;
  if (bid < 256) {
    attn_body<1, 2>(bid, fh2, fl2, fv2, nullptr, Op2, Lp2, 1024, &KVT[0][0]);
  } else if (bid < 288) {
    attn_body<1, 1>(bid - 256, fh4, fl4, fv4, a4, nullptr, nullptr, 256,
                    &KVT[0][0]);
  } else {
    attn_body<2, 4>(bid - 288, fh1, fl1, fv1, nullptr, Op1, Lp1, NPIX,
                    &KVT[0][0]);
  }
}

// ---------------------------------------------------------------------------
// final3: FUSED scale-1 combine (4 partials) + scale-2 combine (2 partials)
// + output assembly. Block = (b, y-row). (unchanged)
// ---------------------------------------------------------------------------
__global__ __launch_bounds__(256) void final3_kernel(
    const float* __restrict__ xin,
    const unsigned short* __restrict__ Op1, const float* __restrict__ Lp1,
    const unsigned short* __restrict__ Op2, const float* __restrict__ Lp2,
    const float* __restrict__ a4, float* __restrict__ out) {
  __shared__ float T[64][65];
  __shared__ float T2[64][66];
  const int tid = threadIdx.x;
  const int y = blockIdx.x & 63;
  const int b = blockIdx.x >> 6;
  const size_t S1 = (size_t)BB * NPIX * CC;
  const size_t T1 = (size_t)BB * NPIX;
  const size_t S2 = (size_t)BB * 1024 * CC;
  const size_t L2 = (size_t)BB * 1024;

  const float ty2 = y * 0.5f - 0.25f;
  const int iy2 = (int)floorf(ty2);
  const float wy2 = ty2 - iy2;
  const int iy20 = max(iy2, 0), iy21 = min(iy2 + 1, 31);

  const int nl = tid >> 2;             // 0..63
  const int ck = (tid & 3) * 16;       // c chunk

  {  // ---- phase 1: combine scale-1 row y (4 partials) ----
    const int n = y * 64 + nl;
    float lv = 0.f;
#pragma unroll
    for (int ks = 0; ks < 4; ++ks)
      lv += Lp1[(size_t)ks * T1 + (size_t)b * NPIX + n];
    const float inv = 1.f / lv;
    float v[16];
#pragma unroll
    for (int j = 0; j < 16; ++j) v[j] = 0.f;
#pragma unroll
    for (int ks = 0; ks < 4; ++ks) {
      const unsigned short* src =
          Op1 + (size_t)ks * S1 + ((size_t)b * NPIX + n) * CC + ck;
      const ushort8 u0 = *(const ushort8*)(src);
      const ushort8 u1 = *(const ushort8*)(src + 8);
#pragma unroll
      for (int j = 0; j < 8; ++j) {
        v[j]     += bf2f(u0[j]);
        v[8 + j] += bf2f(u1[j]);
      }
    }
#pragma unroll
    for (int j = 0; j < 16; ++j) T[ck + j][nl] = v[j] * inv;
  }
  {  // ---- phase 1b: combine scale-2 rows iy20 (nl<32) / iy21 (nl>=32) ----
    const int row = nl >> 5;
    const int ix  = nl & 31;
    const int n2  = (row == 0 ? iy20 : iy21) * 32 + ix;
    float lv = Lp2[(size_t)b * 1024 + n2] + Lp2[L2 + (size_t)b * 1024 + n2];
    const float inv = 1.f / lv;
    float v[16];
#pragma unroll
    for (int j = 0; j < 16; ++j) v[j] = 0.f;
#pragma unroll
    for (int ks = 0; ks < 2; ++ks) {
      const unsigned short* src =
          Op2 + (size_t)ks * S2 + ((size_t)b * 1024 + n2) * CC + ck;
      const ushort8 u0 = *(const ushort8*)(src);
      const ushort8 u1 = *(const ushort8*)(src + 8);
#pragma unroll
      for (int j = 0; j < 8; ++j) {
        v[j]     += bf2f(u0[j]);
        v[8 + j] += bf2f(u1[j]);
      }
    }
#pragma unroll
    for (int j = 0; j < 16; ++j) T2[ck + j][nl] = v[j] * inv;
  }
  __syncthreads();

  // ---- phase 2: assemble output row ----
  const int c  = tid >> 2;
  const int xk = (tid & 3) * 16;
  const float* xrow = xin + (((size_t)b * CC + c) * HH + y) * WW;
  float* orow = out + (((size_t)b * CC + c) * HH + y) * WW;

  const float ty4 = y * 0.25f - 0.375f;
  const int iy4 = (int)floorf(ty4);
  const float wy4 = ty4 - iy4;
  const int iy40 = max(iy4, 0), iy41 = min(iy4 + 1, 15);
  const float* b4 = a4 + (size_t)b * 256 * 64 + c;

#pragma unroll
  for (int j = 0; j < 16; ++j) {
    const int xx = xk + j;
    float r = xrow[xx] + T[c][xx];
    {  // scale 2 (rows pre-combined in T2: cols 0-31 = iy20, 32-63 = iy21)
      const float tx = xx * 0.5f - 0.25f;
      const int ix = (int)floorf(tx);
      const float wx = tx - ix;
      const int ix0 = max(ix, 0), ix1 = min(ix + 1, 31);
      const float v00 = T2[c][ix0],      v01 = T2[c][ix1];
      const float v10 = T2[c][32 + ix0], v11 = T2[c][32 + ix1];
      r += (1.f-wy2)*((1.f-wx)*v00 + wx*v01) + wy2*((1.f-wx)*v10 + wx*v11);
    }
    {  // scale 4
      const float tx = xx * 0.25f - 0.375f;
      const int ix = (int)floorf(tx);
      const float wx = tx - ix;
      const int ix0 = max(ix, 0), ix1 = min(ix + 1, 15);
      const float v00 = b4[(iy40*16+ix0)*64], v01 = b4[(iy40*16+ix1)*64];
      const float v10 = b4[(iy41*16+ix0)*64], v11 = b4[(iy41*16+ix1)*64];
      r += (1.f-wy4)*((1.f-wx)*v00 + wx*v01) + wy4*((1.f-wx)*v10 + wx*v11);
    }
    orow[xx] = r;
  }
}

// ---------------------------------------------------------------------------
extern "C" void kernel_launch(void* const* d_in, const int* in_sizes, int n_in,
                              void* d_out, int out_size, void* d_ws,
                              size_t ws_size, hipStream_t stream) {
  const float* x = (const float*)d_in[0];
  const float* w = (const float*)d_in[1];
  float* out = (float*)d_out;

  unsigned short* fh1 = (unsigned short*)d_ws;            // [8][4096][64] fp16 swz
  unsigned short* fl1 = fh1 + (size_t)BB*NPIX*CC;         // fp16 lo
  unsigned short* fv1 = fl1 + (size_t)BB*NPIX*CC;         // fp16 tile-major V^T
  unsigned short* fh2 = fv1 + (size_t)BB*NPIX*CC;         // [8][1024][64]
  unsigned short* fl2 = fh2 + (size_t)BB*1024*CC;
  unsigned short* fv2 = fl2 + (size_t)BB*1024*CC;
  unsigned short* fh4 = fv2 + (size_t)BB*1024*CC;         // [8][256][64]
  unsigned short* fl4 = fh4 + (size_t)BB*256*CC;
  unsigned short* fv4 = fl4 + (size_t)BB*256*CC;
  unsigned short* Op1 = fv4 + (size_t)BB*256*CC;          // [4][8][4096][64] bf16
  float* Lp1 = (float*)(Op1 + 4*(size_t)BB*NPIX*CC);      // [4][8][4096]
  unsigned short* Op2 = (unsigned short*)(Lp1 + 4*(size_t)BB*NPIX);  // [2][8][1024][64]
  float* Lp2 = (float*)(Op2 + 2*(size_t)BB*1024*CC);      // [2][8][1024]
  float* a4  = Lp2 + 2*(size_t)BB*1024;                   // [8][256][64] fp32

  // Dead-time aliases: WT (dead after conv_mfma) aliases Op2 (attn later)
  unsigned short* wth = (unsigned short*)Op2;             // 72 KB
  unsigned short* wtl = wth + 9*64*64;                    // 72 KB

  wprep_kernel<<<144, 256, 0, stream>>>(w, wth, wtl);
  conv_mfma<<<dim3(64, 8), 256, 0, stream>>>(x, wth, wtl, fh1, fl1, fv1);
  pools_kernel<<<2560, 256, 0, stream>>>(fh1, fl1, fh2, fl2, fv2, fh4, fl4, fv4);
  attn_all<<<1312, 256, 0, stream>>>(fh1, fl1, fv1, Op1, Lp1,
                                     fh2, fl2, fv2, Op2, Lp2,
                                     fh4, fl4, fv4, a4);
  final3_kernel<<<512, 256, 0, stream>>>(x, Op1, Lp1, Op2, Lp2, a4, out);
}

// Round 7
// 140.407 us; speedup vs baseline: 1.2695x; 1.1673x over previous
//
#include <hip/hip_runtime.h>
#include <hip/hip_bf16.h>
#include <math.h>

// Problem constants: x [8,64,64,64] fp32 NCHW, W_std [64,64,3,3] fp32 OIHW.
#define BB 8
#define CC 64
#define HH 64
#define WW 64
#define NPIX (HH*WW)   // 4096
#define LOG2E 1.44269504088896340736f

typedef __attribute__((ext_vector_type(8))) short bf16x8;            // bf16 A/B frag
typedef __attribute__((ext_vector_type(8))) _Float16 half8;          // fp16 A/B frag (K=32)
typedef __attribute__((ext_vector_type(4))) _Float16 half4;          // fp16 A/B frag (K=16)
typedef __attribute__((ext_vector_type(4))) float floatx4;           // MFMA C/D frag
typedef __attribute__((ext_vector_type(8))) unsigned short ushort8;  // 16B unit

__device__ inline unsigned short f2bf(float x) {
  __hip_bfloat16 h = __float2bfloat16(x);
  return *reinterpret_cast<unsigned short*>(&h);
}
__device__ inline unsigned short f2bf_fast(float x) {
  const unsigned u = __float_as_uint(x);
  return (unsigned short)((u + 0x8000u) >> 16);
}
__device__ inline float bf2f(unsigned short u) {
  __hip_bfloat16 h = *reinterpret_cast<__hip_bfloat16*>(&u);
  return __bfloat162float(h);
}
__device__ inline unsigned short f2h(float x) {
  _Float16 h = (_Float16)x;
  return *reinterpret_cast<unsigned short*>(&h);
}
__device__ inline float h2f(unsigned short u) {
  _Float16 h = *reinterpret_cast<_Float16*>(&u);
  return (float)h;
}

// XOR swizzle for K/Q rows: 16B chunks permuted within each 128B row.
__device__ inline int swzoff(int n, int c) {
  return (((c >> 3) ^ (n & 7)) << 3) | (c & 7);
}
// V^T swizzle: b64-granular (round 18 — measured 4.75M -> 0 conflicts).
__device__ inline int swzvslot(int key, int c) {
  return ((((key >> 2) ^ (c & 15)) << 2)) | (key & 3);
}

// 16B global -> LDS DMA (per-lane global scatter OK; LDS dest = base+lane*16)
#define GLD_LDS16(gp, lp)                                                     \
  __builtin_amdgcn_global_load_lds(                                           \
      (const __attribute__((address_space(1))) void*)(gp),                    \
      (__attribute__((address_space(3))) void*)(lp), 16, 0, 0)

// ---------------------------------------------------------------------------
// wprep: WT[tap][o][c] bf16 hi/lo, depthwise Laplacian folded in.
// ---------------------------------------------------------------------------
__global__ __launch_bounds__(256) void wprep_kernel(
    const float* __restrict__ w,
    unsigned short* __restrict__ wth, unsigned short* __restrict__ wtl) {
  const int idx = blockIdx.x * 256 + threadIdx.x;   // 9*64*64 = 36864
  const int c   = idx & 63;
  const int o   = (idx >> 6) & 63;
  const int tap = idx >> 12;
  float v = w[((o * 64 + c) * 9) + tap];
  if (o == c) {
    const float lapk[9] = {0.f, 1.f, 0.f, 1.f, -4.f, 1.f, 0.f, 1.f, 0.f};
    v += lapk[tap];
  }
  const unsigned short hi = f2bf(v);
  wth[(tap * 64 + o) * 64 + c] = hi;
  wtl[(tap * 64 + o) * 64 + c] = f2bf(v - bf2f(hi));
}

// ---------------------------------------------------------------------------
// conv_mfma: implicit-GEMM conv. Round 20: SINGLE-PHASE staging — DMA all
// 3 fp32 x-rows (48KB) into the XS region itself, drain ONCE, copy each
// thread's 48 values to registers, barrier, convert/write the swizzled
// bf16 hi/lo layout in place. 6 barriers -> 3, XLf gone, LDS 64 -> 48KB
// -> 3 blocks/CU.
// ---------------------------------------------------------------------------
__global__ __launch_bounds__(256, 3) void conv_mfma(
    const float* __restrict__ xin,
    const unsigned short* __restrict__ wth,
    const unsigned short* __restrict__ wtl,
    unsigned short* __restrict__ fh, unsigned short* __restrict__ fl,
    unsigned short* __restrict__ fv) {
  __shared__ __align__(16) unsigned short XS[6 * 4096];  // 48KB

  const int tid  = threadIdx.x;
  const int lane = tid & 63;
  const int wave = tid >> 6;
  const int r16  = lane & 15;
  const int quad = lane >> 4;
  const int y = blockIdx.x, b = blockIdx.y;
  const int px = tid & 63, cp = tid >> 6;

  // ---- stage: DMA 3 rows fp32 [c][x] into XS bytes [r*16KB ...] ----
  float* XSf = (float*)XS;
  const float* xb = xin + (size_t)b * CC * NPIX;
#pragma unroll
  for (int r = 0; r < 3; ++r) {
    const int yy = min(max(y - 1 + r, 0), HH - 1);
    const float* xrow = xb + yy * WW;
#pragma unroll
    for (int j = 0; j < 4; ++j) {
      const int cb = (wave * 4 + j) * 4;        // 4 channel-rows per DMA
      const int cl = cb + (lane >> 4);
      const float* g = xrow + (size_t)cl * NPIX + ((lane & 15) << 2);
      GLD_LDS16(g, (char*)XSf + r * 16384 + cb * 256 + lane * 16);
    }
  }
  __syncthreads();                              // single DMA drain

  // ---- copy this thread's 48 values to regs (fp32 region dies next) ----
  float xv[3][16];
#pragma unroll
  for (int r = 0; r < 3; ++r)
#pragma unroll
    for (int j = 0; j < 16; ++j)
      xv[r][j] = XSf[r * 4096 + (cp * 16 + j) * 64 + px];
  __syncthreads();                              // all reads done

  // ---- convert/write swizzled bf16 hi/lo in place ----
#pragma unroll
  for (int r = 0; r < 3; ++r) {
    ushort8 vh[2], vl[2];
#pragma unroll
    for (int j = 0; j < 16; ++j) {
      const float v = xv[r][j];
      const unsigned short hh = f2bf(v);
      vh[j >> 3][j & 7] = hh;
      vl[j >> 3][j & 7] = f2bf(v - bf2f(hh));
    }
    unsigned short* xsh = XS + r * 4096 + px * 64;
    unsigned short* xsl = XS + (3 + r) * 4096 + px * 64;
#pragma unroll
    for (int k = 0; k < 2; ++k) {
      const int ch = cp * 2 + k;
      const int off = ((ch ^ (px & 7)) << 3);
      *(ushort8*)(xsh + off) = vh[k];
      *(ushort8*)(xsl + off) = vl[k];
    }
  }
  __syncthreads();                              // XS ready

  floatx4 acc[4];
#pragma unroll
  for (int t = 0; t < 4; ++t) acc[t] = (floatx4){0.f, 0.f, 0.f, 0.f};
  const bf16x8 ZF = {0, 0, 0, 0, 0, 0, 0, 0};
  const int og = wave * 16 + r16;

#pragma unroll
  for (int tap = 0; tap < 9; ++tap) {
    const int ky = tap / 3, kx = tap % 3;
    const int yy = y + ky - 1;
    if (yy < 0 || yy >= HH) continue;
    const unsigned short* wt = wth + ((tap * 64 + og) << 6);
    const unsigned short* wl = wtl + ((tap * 64 + og) << 6);
    const bf16x8 Wh0 = *(const bf16x8*)(wt + quad * 8);
    const bf16x8 Wh1 = *(const bf16x8*)(wt + 32 + quad * 8);
    const bf16x8 Wl0 = *(const bf16x8*)(wl + quad * 8);
    const bf16x8 Wl1 = *(const bf16x8*)(wl + 32 + quad * 8);
#pragma unroll
    for (int t = 0; t < 4; ++t) {
      const int px2 = t * 16 + r16 + kx - 1;
      const bool ok = (px2 >= 0) && (px2 < WW);
      const int pxc = ok ? px2 : 0;
      const int bh = ky * 4096 + pxc * 64;
      const int bl = bh + 3 * 4096;
      const int o0 = ((quad ^ (pxc & 7)) << 3);
      const int o1 = (((4 + quad) ^ (pxc & 7)) << 3);
      bf16x8 Ah0 = *(const bf16x8*)(XS + bh + o0);
      bf16x8 Ah1 = *(const bf16x8*)(XS + bh + o1);
      bf16x8 Al0 = *(const bf16x8*)(XS + bl + o0);
      bf16x8 Al1 = *(const bf16x8*)(XS + bl + o1);
      if (!ok) { Ah0 = ZF; Ah1 = ZF; Al0 = ZF; Al1 = ZF; }
      acc[t] = __builtin_amdgcn_mfma_f32_16x16x32_bf16(Ah0, Wh0, acc[t], 0, 0, 0);
      acc[t] = __builtin_amdgcn_mfma_f32_16x16x32_bf16(Ah1, Wh1, acc[t], 0, 0, 0);
      acc[t] = __builtin_amdgcn_mfma_f32_16x16x32_bf16(Ah0, Wl0, acc[t], 0, 0, 0);
      acc[t] = __builtin_amdgcn_mfma_f32_16x16x32_bf16(Ah1, Wl1, acc[t], 0, 0, 0);
      acc[t] = __builtin_amdgcn_mfma_f32_16x16x32_bf16(Al0, Wh0, acc[t], 0, 0, 0);
      acc[t] = __builtin_amdgcn_mfma_f32_16x16x32_bf16(Al1, Wh1, acc[t], 0, 0, 0);
    }
  }

#pragma unroll
  for (int t = 0; t < 4; ++t)
#pragma unroll
    for (int r = 0; r < 4; ++r) {
      const int key = t * 16 + quad * 4 + r;
      const int n = y * WW + key;
      const float v = acc[t][r];
      const unsigned short hi = f2h(v);               // fp16 hi
      const unsigned short lo = f2h(v - h2f(hi));     // fp16 lo
      fh[((size_t)b * NPIX + n) * CC + swzoff(n, og)] = hi;
      fl[((size_t)b * NPIX + n) * CC + swzoff(n, og)] = lo;
      fv[(((size_t)b * (NPIX >> 6) + y) * CC + og) * 64 + swzvslot(key, og)] =
          f2h(v);                                     // V^T fp16
    }
}

// ---------------------------------------------------------------------------
// pools: merged pool2 + pool4-direct (unchanged).
// ---------------------------------------------------------------------------
__global__ void pools_kernel(const unsigned short* __restrict__ in_h,
                             const unsigned short* __restrict__ in_l,
                             unsigned short* __restrict__ h2,
                             unsigned short* __restrict__ l2,
                             unsigned short* __restrict__ v2,
                             unsigned short* __restrict__ h4,
                             unsigned short* __restrict__ l4,
                             unsigned short* __restrict__ v4) {
  const int bid = blockIdx.x;
  if (bid < 2048) {           // ---- pool2: 64x64 -> 32x32 ----
    const int idx = bid * 256 + threadIdx.x;
    const int c  = idx & 63;
    const int t  = idx >> 6;
    const int xo = t & 31;
    const int yo = (t >> 5) & 31;
    const int b  = t >> 10;
    const size_t ibase = (size_t)b * NPIX * CC;
    float s = 0.f;
#pragma unroll
    for (int dy = 0; dy < 2; ++dy)
#pragma unroll
      for (int dx = 0; dx < 2; ++dx) {
        const int nin = (2*yo+dy) * 64 + (2*xo+dx);
        const size_t a = ibase + (size_t)nin * CC + swzoff(nin, c);
        s += h2f(in_h[a]) + h2f(in_l[a]);
      }
    const float vv = 0.25f * s;
    const unsigned short hi = f2h(vv);
    const int nout = yo * 32 + xo;
    const size_t ob = ((size_t)b * 1024 + nout) * CC + swzoff(nout, c);
    h2[ob] = hi;
    l2[ob] = f2h(vv - h2f(hi));
    v2[(((size_t)b * 16 + (nout >> 6)) * CC + c) * 64 + swzvslot(nout & 63, c)] =
        f2h(vv);
  } else {                    // ---- pool4: 64x64 -> 16x16 (direct) ----
    const int idx = (bid - 2048) * 256 + threadIdx.x;
    const int c  = idx & 63;
    const int t  = idx >> 6;
    const int xo = t & 15;
    const int yo = (t >> 4) & 15;
    const int b  = t >> 8;
    const size_t ibase = (size_t)b * NPIX * CC;
    float s = 0.f;
#pragma unroll
    for (int dy = 0; dy < 4; ++dy)
#pragma unroll
      for (int dx = 0; dx < 4; ++dx) {
        const int nin = (4*yo+dy) * 64 + (4*xo+dx);
        const size_t a = ibase + (size_t)nin * CC + swzoff(nin, c);
        s += h2f(in_h[a]) + h2f(in_l[a]);
      }
    const float vv = 0.0625f * s;
    const unsigned short hi = f2h(vv);
    const int nout = yo * 16 + xo;
    const size_t ob = ((size_t)b * 256 + nout) * CC + swzoff(nout, c);
    h4[ob] = hi;
    l4[ob] = f2h(vv - h2f(hi));
    v4[(((size_t)b * 4 + (nout >> 6)) * CC + c) * 64 + swzvslot(nout & 63, c)] =
        f2h(vv);
  }
}

// ---------------------------------------------------------------------------
// MFMA flash attention <NH, KS> — round-19 structure (S = Qh·Kh only);
// round 20: pk-cvt P pack + pointer-advance DMA addressing.
// round 21: -Mq folded into QK^T MFMA C-in.
// round 22: launch_bounds back to 4 (5 spilled O/Q to scratch).
// round 23/24: PV tt-pair K=32 merge with bounded live ranges + fence.
// round 25: V-direct-from-global — REVERTED (attn 48->88us: unhideable L2
// gather latency behind the fence + L2 churn doubled HBM write traffic).
// round 26: s_setprio around MFMA clusters — REVERTED (attn 48->72us:
// FETCH 8->39MB / WRITE 19->68MB at unchanged VGPR=64 — NOT spill but L2
// churn: priority arbitration desynchronized the 32 same-XCD blocks that
// share each (b,ks) K/V slice; lines evicted before all sharers read them.
// T5 is poison when the memory economy relies on cross-block temporal
// coherence).
// round 27: exact round-24 structure restored (best measured: 137.5us).
// ---------------------------------------------------------------------------
template <int NH, int KS>
__device__ __forceinline__ void attn_body(
    int bid,
    const unsigned short* __restrict__ fh,
    const unsigned short* __restrict__ fl,
    const unsigned short* __restrict__ fv,
    float* __restrict__ outF, unsigned short* __restrict__ outB,
    float* __restrict__ outL, int N,
    unsigned short* KVT) {
  const int tid  = threadIdx.x;
  const int lane = tid & 63;
  const int wave = tid >> 6;
  const int b    = bid & 7;              // XCD-local batch grouping
  const int rest = bid >> 3;
  const int nq   = N / (64 * NH);
  const int qt   = rest % nq;
  const int ks   = rest / nq;            // 0..KS-1
  const int q0   = qt * (64 * NH) + wave * (16 * NH);
  const int nt   = (N >> 6) / KS;
  const int t0   = ks * nt;
  const int r16  = lane & 15;
  const int quad = lane >> 4;
  const int swb  = r16 & 7;

  const unsigned short* fhB = fh + (size_t)b * N * CC;   // fp16 K/Q hi
  const unsigned short* flB = fl + (size_t)b * N * CC;   // fp16 Q lo
  const unsigned short* fvB = fv + (size_t)b * N * CC;   // fp16 tile-major V^T

  // ---- per-wave DMA source pointers (advance by 4096 per tile) ----
  const unsigned short* gp[4];
  int ldsoff[4];
#pragma unroll
  for (int j = 0; j < 4; ++j) {
    const int cid = wave * 4 + j;
    const int arr = cid >> 3, sub = (cid & 7) << 9;
    gp[j] = (arr == 0 ? fhB : fvB) + (size_t)t0 * 4096 + sub + lane * 8;
    ldsoff[j] = arr * 4096 + sub + lane * 8;
  }
  // ---- stage first tile ----
#pragma unroll
  for (int j = 0; j < 4; ++j) {
    GLD_LDS16(gp[j], KVT + ldsoff[j]);
    gp[j] += 4096;
  }

  // ---- Q fragments per half: f = h+l (exact M), Qh = fp16(f*log2e) ----
  half8 Qh[NH][2];
  float Mq[NH];
#pragma unroll
  for (int h = 0; h < NH; ++h) {
    float Mpart = 0.f;
#pragma unroll
    for (int kss = 0; kss < 2; ++kss) {
      const size_t off = (size_t)(q0 + h * 16 + r16) * CC
                         + ((((kss << 2) + quad) ^ swb) << 3);
      const ushort8 hh = *(const ushort8*)(fhB + off);
      const ushort8 ll = *(const ushort8*)(flB + off);
      half8 sh;
#pragma unroll
      for (int j = 0; j < 8; ++j) {
        const float f = h2f(hh[j]) + h2f(ll[j]);
        const float g = f * LOG2E;
        sh[j] = (_Float16)g;
        Mpart += g * f;                  // = log2e * sum f^2 (partial)
      }
      Qh[h][kss] = sh;
    }
    Mpart += __shfl_xor(Mpart, 16, 64);
    Mpart += __shfl_xor(Mpart, 32, 64);  // M for q = r16, replicated
    Mq[h] = Mpart;                       // per-lane SCALAR (q = r16)
  }

  // ---- -Mq as an MFMA C-in fragment: QK^T lands pre-shifted ----
  floatx4 nMq[NH];
#pragma unroll
  for (int h = 0; h < NH; ++h)
    nMq[h] = (floatx4){-Mq[h], -Mq[h], -Mq[h], -Mq[h]};

  floatx4 O[NH][4];
  float lloc[NH];
#pragma unroll
  for (int h = 0; h < NH; ++h) {
    lloc[h] = 0.f;
#pragma unroll
    for (int ch = 0; ch < 4; ++ch) O[h][ch] = (floatx4){0.f, 0.f, 0.f, 0.f};
  }

  int koff[2];
#pragma unroll
  for (int kss = 0; kss < 2; ++kss) koff[kss] = (((kss << 2) + quad) ^ swb) << 3;

  for (int t = 0; t < nt; ++t) {
    const int cur = t & 1;
    __syncthreads();                    // drains DMA for tile t, syncs block
    if (t + 1 < nt) {                   // issue DMA for tile t+1 now
      unsigned short* dst = KVT + (cur ^ 1) * 8192;
#pragma unroll
      for (int j = 0; j < 4; ++j) {
        GLD_LDS16(gp[j], dst + ldsoff[j]);
        gp[j] += 4096;
      }
    }
    const unsigned short* kh = KVT + cur * 8192;   // fp16 K hi
    const unsigned short* vt = kh + 4096;          // fp16 V^T

#pragma unroll
    for (int tp = 0; tp < 2; ++tp) {    // tt-pair: keys [tp*32, tp*32+32)
      const int tt0 = tp * 2, tt1 = tp * 2 + 1;
      // ---- S^T for both halves; K fragments transient per scope ----
      floatx4 s0[NH], s1[NH];
      {
        const int kb = (tt0 * 16 + r16) * 64;
        const half8 Ka = *(const half8*)(kh + kb + koff[0]);
        const half8 Kb = *(const half8*)(kh + kb + koff[1]);
#pragma unroll
        for (int h = 0; h < NH; ++h) {
          s0[h] = __builtin_amdgcn_mfma_f32_16x16x32_f16(Ka, Qh[h][0], nMq[h], 0, 0, 0);
          s0[h] = __builtin_amdgcn_mfma_f32_16x16x32_f16(Kb, Qh[h][1], s0[h], 0, 0, 0);
        }
      }
      {
        const int kb = (tt1 * 16 + r16) * 64;
        const half8 Ka = *(const half8*)(kh + kb + koff[0]);
        const half8 Kb = *(const half8*)(kh + kb + koff[1]);
#pragma unroll
        for (int h = 0; h < NH; ++h) {
          s1[h] = __builtin_amdgcn_mfma_f32_16x16x32_f16(Ka, Qh[h][0], nMq[h], 0, 0, 0);
          s1[h] = __builtin_amdgcn_mfma_f32_16x16x32_f16(Kb, Qh[h][1], s1[h], 0, 0, 0);
        }
      }
      // ---- fixed-shift softmax + pack P pair into K=32 A-layout ----
      half8 Pf8[NH];
#pragma unroll
      for (int h = 0; h < NH; ++h) {
        const float p0 = __builtin_amdgcn_exp2f(s0[h][0]);
        const float p1 = __builtin_amdgcn_exp2f(s0[h][1]);
        const float p2 = __builtin_amdgcn_exp2f(s0[h][2]);
        const float p3 = __builtin_amdgcn_exp2f(s0[h][3]);
        const float p4 = __builtin_amdgcn_exp2f(s1[h][0]);
        const float p5 = __builtin_amdgcn_exp2f(s1[h][1]);
        const float p6 = __builtin_amdgcn_exp2f(s1[h][2]);
        const float p7 = __builtin_amdgcn_exp2f(s1[h][3]);
        lloc[h] += ((p0 + p1) + (p2 + p3)) + ((p4 + p5) + (p6 + p7));
        const auto a0 = __builtin_amdgcn_cvt_pkrtz(p0, p1);  // __fp16 x2
        const auto a1 = __builtin_amdgcn_cvt_pkrtz(p2, p3);
        const auto a2 = __builtin_amdgcn_cvt_pkrtz(p4, p5);
        const auto a3 = __builtin_amdgcn_cvt_pkrtz(p6, p7);
        Pf8[h] = (half8){(_Float16)a0[0], (_Float16)a0[1],
                         (_Float16)a1[0], (_Float16)a1[1],
                         (_Float16)a2[0], (_Float16)a2[1],
                         (_Float16)a3[0], (_Float16)a3[1]};
      }
      // Pressure fence: V loads + addressing may NOT hoist above this point.
      __builtin_amdgcn_sched_barrier(0);
      // ---- PV: per-ch V pair load, consumed immediately ----
      const int vs0 = (((tt0 * 4 + quad) ^ r16) << 2);
      const int vs1 = (((tt1 * 4 + quad) ^ r16) << 2);
#pragma unroll
      for (int ch = 0; ch < 4; ++ch) {
        const half4 va = *(const half4*)(vt + (ch * 16 + r16) * 64 + vs0);
        const half4 vb = *(const half4*)(vt + (ch * 16 + r16) * 64 + vs1);
        const half8 Vf8 = (half8){va[0], va[1], va[2], va[3],
                                  vb[0], vb[1], vb[2], vb[3]};
#pragma unroll
        for (int h = 0; h < NH; ++h)
          O[h][ch] = __builtin_amdgcn_mfma_f32_16x16x32_f16(Pf8[h], Vf8,
                                                            O[h][ch], 0, 0, 0);
      }
    }
  }

  // ---- epilogue: l = reduce(lloc), spread to rows, store ----
#pragma unroll
  for (int h = 0; h < NH; ++h) {
    float lt = lloc[h];
    lt += __shfl_xor(lt, 16, 64);
    lt += __shfl_xor(lt, 32, 64);       // l for q = r16, replicated
    float lq[4];
#pragma unroll
    for (int r = 0; r < 4; ++r) lq[r] = __shfl(lt, quad * 4 + r, 16);
    if (KS != 1 && r16 == 0) {
#pragma unroll
      for (int r = 0; r < 4; ++r)
        outL[(size_t)ks * BB * N + (size_t)b * N + q0 + h * 16 + quad * 4 + r] =
            lq[r];
    }
#pragma unroll
    for (int ch = 0; ch < 4; ++ch)
#pragma unroll
      for (int r = 0; r < 4; ++r) {
        const size_t qi = (size_t)b * N + q0 + h * 16 + quad * 4 + r;
        if (KS == 1) {
          outF[qi * CC + ch * 16 + r16] = O[h][ch][r] / lq[r];
        } else {
          outB[(size_t)ks * BB * N * CC + qi * CC + ch * 16 + r16] =
              f2bf_fast(O[h][ch][r]);
        }
      }
  }
}

// Merged dispatch — short blocks first (tail-fill), segment offsets ≡0 mod 8
// so b = bid&7 XCD grouping is preserved.
// [0,256) scale-2 NH=1/KS=2; [256,288) scale-4 NH=1/KS=1;
// [288,1312) scale-1 NH=2/KS=4. LDS 32KB -> 4 blocks/CU (VGPR cap 128).
__global__ __launch_bounds__(256, 4) void attn_all(
    const unsigned short* __restrict__ fh1, const unsigned short* __restrict__ fl1,
    const unsigned short* __restrict__ fv1,
    unsigned short* __restrict__ Op1, float* __restrict__ Lp1,
    const unsigned short* __restrict__ fh2, const unsigned short* __restrict__ fl2,
    const unsigned short* __restrict__ fv2,
    unsigned short* __restrict__ Op2, float* __restrict__ Lp2,
    const unsigned short* __restrict__ fh4, const unsigned short* __restrict__ fl4,
    const unsigned short* __restrict__ fv4, float* __restrict__ a4) {
  __shared__ __align__(16) unsigned short KVT[2][2 * 4096];
  const int bid = blockIdx.x;
  if (bid < 256) {
    attn_body<1, 2>(bid, fh2, fl2, fv2, nullptr, Op2, Lp2, 1024, &KVT[0][0]);
  } else if (bid < 288) {
    attn_body<1, 1>(bid - 256, fh4, fl4, fv4, a4, nullptr, nullptr, 256,
                    &KVT[0][0]);
  } else {
    attn_body<2, 4>(bid - 288, fh1, fl1, fv1, nullptr, Op1, Lp1, NPIX,
                    &KVT[0][0]);
  }
}

// ---------------------------------------------------------------------------
// final3: FUSED scale-1 combine (4 partials) + scale-2 combine (2 partials)
// + output assembly. Block = (b, y-row). (unchanged)
// ---------------------------------------------------------------------------
__global__ __launch_bounds__(256) void final3_kernel(
    const float* __restrict__ xin,
    const unsigned short* __restrict__ Op1, const float* __restrict__ Lp1,
    const unsigned short* __restrict__ Op2, const float* __restrict__ Lp2,
    const float* __restrict__ a4, float* __restrict__ out) {
  __shared__ float T[64][65];
  __shared__ float T2[64][66];
  const int tid = threadIdx.x;
  const int y = blockIdx.x & 63;
  const int b = blockIdx.x >> 6;
  const size_t S1 = (size_t)BB * NPIX * CC;
  const size_t T1 = (size_t)BB * NPIX;
  const size_t S2 = (size_t)BB * 1024 * CC;
  const size_t L2 = (size_t)BB * 1024;

  const float ty2 = y * 0.5f - 0.25f;
  const int iy2 = (int)floorf(ty2);
  const float wy2 = ty2 - iy2;
  const int iy20 = max(iy2, 0), iy21 = min(iy2 + 1, 31);

  const int nl = tid >> 2;             // 0..63
  const int ck = (tid & 3) * 16;       // c chunk

  {  // ---- phase 1: combine scale-1 row y (4 partials) ----
    const int n = y * 64 + nl;
    float lv = 0.f;
#pragma unroll
    for (int ks = 0; ks < 4; ++ks)
      lv += Lp1[(size_t)ks * T1 + (size_t)b * NPIX + n];
    const float inv = 1.f / lv;
    float v[16];
#pragma unroll
    for (int j = 0; j < 16; ++j) v[j] = 0.f;
#pragma unroll
    for (int ks = 0; ks < 4; ++ks) {
      const unsigned short* src =
          Op1 + (size_t)ks * S1 + ((size_t)b * NPIX + n) * CC + ck;
      const ushort8 u0 = *(const ushort8*)(src);
      const ushort8 u1 = *(const ushort8*)(src + 8);
#pragma unroll
      for (int j = 0; j < 8; ++j) {
        v[j]     += bf2f(u0[j]);
        v[8 + j] += bf2f(u1[j]);
      }
    }
#pragma unroll
    for (int j = 0; j < 16; ++j) T[ck + j][nl] = v[j] * inv;
  }
  {  // ---- phase 1b: combine scale-2 rows iy20 (nl<32) / iy21 (nl>=32) ----
    const int row = nl >> 5;
    const int ix  = nl & 31;
    const int n2  = (row == 0 ? iy20 : iy21) * 32 + ix;
    float lv = Lp2[(size_t)b * 1024 + n2] + Lp2[L2 + (size_t)b * 1024 + n2];
    const float inv = 1.f / lv;
    float v[16];
#pragma unroll
    for (int j = 0; j < 16; ++j) v[j] = 0.f;
#pragma unroll
    for (int ks = 0; ks < 2; ++ks) {
      const unsigned short* src =
          Op2 + (size_t)ks * S2 + ((size_t)b * 1024 + n2) * CC + ck;
      const ushort8 u0 = *(const ushort8*)(src);
      const ushort8 u1 = *(const ushort8*)(src + 8);
#pragma unroll
      for (int j = 0; j < 8; ++j) {
        v[j]     += bf2f(u0[j]);
        v[8 + j] += bf2f(u1[j]);
      }
    }
#pragma unroll
    for (int j = 0; j < 16; ++j) T2[ck + j][nl] = v[j] * inv;
  }
  __syncthreads();

  // ---- phase 2: assemble output row ----
  const int c  = tid >> 2;
  const int xk = (tid & 3) * 16;
  const float* xrow = xin + (((size_t)b * CC + c) * HH + y) * WW;
  float* orow = out + (((size_t)b * CC + c) * HH + y) * WW;

  const float ty4 = y * 0.25f - 0.375f;
  const int iy4 = (int)floorf(ty4);
  const float wy4 = ty4 - iy4;
  const int iy40 = max(iy4, 0), iy41 = min(iy4 + 1, 15);
  const float* b4 = a4 + (size_t)b * 256 * 64 + c;

#pragma unroll
  for (int j = 0; j < 16; ++j) {
    const int xx = xk + j;
    float r = xrow[xx] + T[c][xx];
    {  // scale 2 (rows pre-combined in T2: cols 0-31 = iy20, 32-63 = iy21)
      const float tx = xx * 0.5f - 0.25f;
      const int ix = (int)floorf(tx);
      const float wx = tx - ix;
      const int ix0 = max(ix, 0), ix1 = min(ix + 1, 31);
      const float v00 = T2[c][ix0],      v01 = T2[c][ix1];
      const float v10 = T2[c][32 + ix0], v11 = T2[c][32 + ix1];
      r += (1.f-wy2)*((1.f-wx)*v00 + wx*v01) + wy2*((1.f-wx)*v10 + wx*v11);
    }
    {  // scale 4
      const float tx = xx * 0.25f - 0.375f;
      const int ix = (int)floorf(tx);
      const float wx = tx - ix;
      const int ix0 = max(ix, 0), ix1 = min(ix + 1, 15);
      const float v00 = b4[(iy40*16+ix0)*64], v01 = b4[(iy40*16+ix1)*64];
      const float v10 = b4[(iy41*16+ix0)*64], v11 = b4[(iy41*16+ix1)*64];
      r += (1.f-wy4)*((1.f-wx)*v00 + wx*v01) + wy4*((1.f-wx)*v10 + wx*v11);
    }
    orow[xx] = r;
  }
}

// ---------------------------------------------------------------------------
extern "C" void kernel_launch(void* const* d_in, const int* in_sizes, int n_in,
                              void* d_out, int out_size, void* d_ws,
                              size_t ws_size, hipStream_t stream) {
  const float* x = (const float*)d_in[0];
  const float* w = (const float*)d_in[1];
  float* out = (float*)d_out;

  unsigned short* fh1 = (unsigned short*)d_ws;            // [8][4096][64] fp16 swz
  unsigned short* fl1 = fh1 + (size_t)BB*NPIX*CC;         // fp16 lo
  unsigned short* fv1 = fl1 + (size_t)BB*NPIX*CC;         // fp16 tile-major V^T
  unsigned short* fh2 = fv1 + (size_t)BB*NPIX*CC;         // [8][1024][64]
  unsigned short* fl2 = fh2 + (size_t)BB*1024*CC;
  unsigned short* fv2 = fl2 + (size_t)BB*1024*CC;
  unsigned short* fh4 = fv2 + (size_t)BB*1024*CC;         // [8][256][64]
  unsigned short* fl4 = fh4 + (size_t)BB*256*CC;
  unsigned short* fv4 = fl4 + (size_t)BB*256*CC;
  unsigned short* Op1 = fv4 + (size_t)BB*256*CC;          // [4][8][4096][64] bf16
  float* Lp1 = (float*)(Op1 + 4*(size_t)BB*NPIX*CC);      // [4][8][4096]
  unsigned short* Op2 = (unsigned short*)(Lp1 + 4*(size_t)BB*NPIX);  // [2][8][1024][64]
  float* Lp2 = (float*)(Op2 + 2*(size_t)BB*1024*CC);      // [2][8][1024]
  float* a4  = Lp2 + 2*(size_t)BB*1024;                   // [8][256][64] fp32

  // Dead-time aliases: WT (dead after conv_mfma) aliases Op2 (attn later)
  unsigned short* wth = (unsigned short*)Op2;             // 72 KB
  unsigned short* wtl = wth + 9*64*64;                    // 72 KB

  wprep_kernel<<<144, 256, 0, stream>>>(w, wth, wtl);
  conv_mfma<<<dim3(64, 8), 256, 0, stream>>>(x, wth, wtl, fh1, fl1, fv1);
  pools_kernel<<<2560, 256, 0, stream>>>(fh1, fl1, fh2, fl2, fv2, fh4, fl4, fv4);
  attn_all<<<1312, 256, 0, stream>>>(fh1, fl1, fv1, Op1, Lp1,
                                     fh2, fl2, fv2, Op2, Lp2,
                                     fh4, fl4, fv4, a4);
  final3_kernel<<<512, 256, 0, stream>>>(x, Op1, Lp1, Op2, Lp2, a4, out);
}

// Round 10
// 136.626 us; speedup vs baseline: 1.3046x; 1.0277x over previous
//
#include <hip/hip_runtime.h>
#include <hip/hip_bf16.h>
#include <math.h>

// Problem constants: x [8,64,64,64] fp32 NCHW, W_std [64,64,3,3] fp32 OIHW.
#define BB 8
#define CC 64
#define HH 64
#define WW 64
#define NPIX (HH*WW)   // 4096
#define LOG2E 1.44269504088896340736f

typedef __attribute__((ext_vector_type(8))) short bf16x8;            // bf16 A/B frag
typedef __attribute__((ext_vector_type(8))) _Float16 half8;          // fp16 A/B frag (K=32)
typedef __attribute__((ext_vector_type(4))) _Float16 half4;          // fp16 A/B frag (K=16)
typedef __attribute__((ext_vector_type(2))) __fp16 fp16x2;           // cvt_pkrtz result
typedef __attribute__((ext_vector_type(4))) float floatx4;           // MFMA C/D frag
typedef __attribute__((ext_vector_type(8))) unsigned short ushort8;  // 16B unit

__device__ inline unsigned short f2bf(float x) {
  __hip_bfloat16 h = __float2bfloat16(x);
  return *reinterpret_cast<unsigned short*>(&h);
}
__device__ inline unsigned short f2bf_fast(float x) {
  const unsigned u = __float_as_uint(x);
  return (unsigned short)((u + 0x8000u) >> 16);
}
__device__ inline float bf2f(unsigned short u) {
  __hip_bfloat16 h = *reinterpret_cast<__hip_bfloat16*>(&u);
  return __bfloat162float(h);
}
__device__ inline unsigned short f2h(float x) {
  _Float16 h = (_Float16)x;
  return *reinterpret_cast<unsigned short*>(&h);
}
__device__ inline float h2f(unsigned short u) {
  _Float16 h = *reinterpret_cast<_Float16*>(&u);
  return (float)h;
}

// XOR swizzle for K/Q rows: 16B chunks permuted within each 128B row.
__device__ inline int swzoff(int n, int c) {
  return (((c >> 3) ^ (n & 7)) << 3) | (c & 7);
}
// V^T swizzle: b64-granular (round 18 — measured 4.75M -> 0 conflicts).
__device__ inline int swzvslot(int key, int c) {
  return ((((key >> 2) ^ (c & 15)) << 2)) | (key & 3);
}

// 16B global -> LDS DMA (per-lane global scatter OK; LDS dest = base+lane*16)
#define GLD_LDS16(gp, lp)                                                     \
  __builtin_amdgcn_global_load_lds(                                           \
      (const __attribute__((address_space(1))) void*)(gp),                    \
      (__attribute__((address_space(3))) void*)(lp), 16, 0, 0)

// ---------------------------------------------------------------------------
// wprep: WT[tap][o][c] bf16 hi/lo, depthwise Laplacian folded in.
// ---------------------------------------------------------------------------
__global__ __launch_bounds__(256) void wprep_kernel(
    const float* __restrict__ w,
    unsigned short* __restrict__ wth, unsigned short* __restrict__ wtl) {
  const int idx = blockIdx.x * 256 + threadIdx.x;   // 9*64*64 = 36864
  const int c   = idx & 63;
  const int o   = (idx >> 6) & 63;
  const int tap = idx >> 12;
  float v = w[((o * 64 + c) * 9) + tap];
  if (o == c) {
    const float lapk[9] = {0.f, 1.f, 0.f, 1.f, -4.f, 1.f, 0.f, 1.f, 0.f};
    v += lapk[tap];
  }
  const unsigned short hi = f2bf(v);
  wth[(tap * 64 + o) * 64 + c] = hi;
  wtl[(tap * 64 + o) * 64 + c] = f2bf(v - bf2f(hi));
}

// ---------------------------------------------------------------------------
// conv_mfma: implicit-GEMM conv. Round 20: SINGLE-PHASE staging — DMA all
// 3 fp32 x-rows (48KB) into the XS region itself, drain ONCE, copy each
// thread's 48 values to registers, barrier, convert/write the swizzled
// bf16 hi/lo layout in place. 6 barriers -> 3, XLf gone, LDS 64 -> 48KB
// -> 3 blocks/CU.
// ---------------------------------------------------------------------------
__global__ __launch_bounds__(256, 3) void conv_mfma(
    const float* __restrict__ xin,
    const unsigned short* __restrict__ wth,
    const unsigned short* __restrict__ wtl,
    unsigned short* __restrict__ fh, unsigned short* __restrict__ fl,
    unsigned short* __restrict__ fv) {
  __shared__ __align__(16) unsigned short XS[6 * 4096];  // 48KB

  const int tid  = threadIdx.x;
  const int lane = tid & 63;
  const int wave = tid >> 6;
  const int r16  = lane & 15;
  const int quad = lane >> 4;
  const int y = blockIdx.x, b = blockIdx.y;
  const int px = tid & 63, cp = tid >> 6;

  // ---- stage: DMA 3 rows fp32 [c][x] into XS bytes [r*16KB ...] ----
  float* XSf = (float*)XS;
  const float* xb = xin + (size_t)b * CC * NPIX;
#pragma unroll
  for (int r = 0; r < 3; ++r) {
    const int yy = min(max(y - 1 + r, 0), HH - 1);
    const float* xrow = xb + yy * WW;
#pragma unroll
    for (int j = 0; j < 4; ++j) {
      const int cb = (wave * 4 + j) * 4;        // 4 channel-rows per DMA
      const int cl = cb + (lane >> 4);
      const float* g = xrow + (size_t)cl * NPIX + ((lane & 15) << 2);
      GLD_LDS16(g, (char*)XSf + r * 16384 + cb * 256 + lane * 16);
    }
  }
  __syncthreads();                              // single DMA drain

  // ---- copy this thread's 48 values to regs (fp32 region dies next) ----
  float xv[3][16];
#pragma unroll
  for (int r = 0; r < 3; ++r)
#pragma unroll
    for (int j = 0; j < 16; ++j)
      xv[r][j] = XSf[r * 4096 + (cp * 16 + j) * 64 + px];
  __syncthreads();                              // all reads done

  // ---- convert/write swizzled bf16 hi/lo in place ----
#pragma unroll
  for (int r = 0; r < 3; ++r) {
    ushort8 vh[2], vl[2];
#pragma unroll
    for (int j = 0; j < 16; ++j) {
      const float v = xv[r][j];
      const unsigned short hh = f2bf(v);
      vh[j >> 3][j & 7] = hh;
      vl[j >> 3][j & 7] = f2bf(v - bf2f(hh));
    }
    unsigned short* xsh = XS + r * 4096 + px * 64;
    unsigned short* xsl = XS + (3 + r) * 4096 + px * 64;
#pragma unroll
    for (int k = 0; k < 2; ++k) {
      const int ch = cp * 2 + k;
      const int off = ((ch ^ (px & 7)) << 3);
      *(ushort8*)(xsh + off) = vh[k];
      *(ushort8*)(xsl + off) = vl[k];
    }
  }
  __syncthreads();                              // XS ready

  floatx4 acc[4];
#pragma unroll
  for (int t = 0; t < 4; ++t) acc[t] = (floatx4){0.f, 0.f, 0.f, 0.f};
  const bf16x8 ZF = {0, 0, 0, 0, 0, 0, 0, 0};
  const int og = wave * 16 + r16;

#pragma unroll
  for (int tap = 0; tap < 9; ++tap) {
    const int ky = tap / 3, kx = tap % 3;
    const int yy = y + ky - 1;
    if (yy < 0 || yy >= HH) continue;
    const unsigned short* wt = wth + ((tap * 64 + og) << 6);
    const unsigned short* wl = wtl + ((tap * 64 + og) << 6);
    const bf16x8 Wh0 = *(const bf16x8*)(wt + quad * 8);
    const bf16x8 Wh1 = *(const bf16x8*)(wt + 32 + quad * 8);
    const bf16x8 Wl0 = *(const bf16x8*)(wl + quad * 8);
    const bf16x8 Wl1 = *(const bf16x8*)(wl + 32 + quad * 8);
#pragma unroll
    for (int t = 0; t < 4; ++t) {
      const int px2 = t * 16 + r16 + kx - 1;
      const bool ok = (px2 >= 0) && (px2 < WW);
      const int pxc = ok ? px2 : 0;
      const int bh = ky * 4096 + pxc * 64;
      const int bl = bh + 3 * 4096;
      const int o0 = ((quad ^ (pxc & 7)) << 3);
      const int o1 = (((4 + quad) ^ (pxc & 7)) << 3);
      bf16x8 Ah0 = *(const bf16x8*)(XS + bh + o0);
      bf16x8 Ah1 = *(const bf16x8*)(XS + bh + o1);
      bf16x8 Al0 = *(const bf16x8*)(XS + bl + o0);
      bf16x8 Al1 = *(const bf16x8*)(XS + bl + o1);
      if (!ok) { Ah0 = ZF; Ah1 = ZF; Al0 = ZF; Al1 = ZF; }
      acc[t] = __builtin_amdgcn_mfma_f32_16x16x32_bf16(Ah0, Wh0, acc[t], 0, 0, 0);
      acc[t] = __builtin_amdgcn_mfma_f32_16x16x32_bf16(Ah1, Wh1, acc[t], 0, 0, 0);
      acc[t] = __builtin_amdgcn_mfma_f32_16x16x32_bf16(Ah0, Wl0, acc[t], 0, 0, 0);
      acc[t] = __builtin_amdgcn_mfma_f32_16x16x32_bf16(Ah1, Wl1, acc[t], 0, 0, 0);
      acc[t] = __builtin_amdgcn_mfma_f32_16x16x32_bf16(Al0, Wh0, acc[t], 0, 0, 0);
      acc[t] = __builtin_amdgcn_mfma_f32_16x16x32_bf16(Al1, Wh1, acc[t], 0, 0, 0);
    }
  }

#pragma unroll
  for (int t = 0; t < 4; ++t)
#pragma unroll
    for (int r = 0; r < 4; ++r) {
      const int key = t * 16 + quad * 4 + r;
      const int n = y * WW + key;
      const float v = acc[t][r];
      const unsigned short hi = f2h(v);               // fp16 hi
      const unsigned short lo = f2h(v - h2f(hi));     // fp16 lo
      fh[((size_t)b * NPIX + n) * CC + swzoff(n, og)] = hi;
      fl[((size_t)b * NPIX + n) * CC + swzoff(n, og)] = lo;
      fv[(((size_t)b * (NPIX >> 6) + y) * CC + og) * 64 + swzvslot(key, og)] =
          f2h(v);                                     // V^T fp16
    }
}

// ---------------------------------------------------------------------------
// pools: merged pool2 + pool4-direct (unchanged).
// ---------------------------------------------------------------------------
__global__ void pools_kernel(const unsigned short* __restrict__ in_h,
                             const unsigned short* __restrict__ in_l,
                             unsigned short* __restrict__ h2,
                             unsigned short* __restrict__ l2,
                             unsigned short* __restrict__ v2,
                             unsigned short* __restrict__ h4,
                             unsigned short* __restrict__ l4,
                             unsigned short* __restrict__ v4) {
  const int bid = blockIdx.x;
  if (bid < 2048) {           // ---- pool2: 64x64 -> 32x32 ----
    const int idx = bid * 256 + threadIdx.x;
    const int c  = idx & 63;
    const int t  = idx >> 6;
    const int xo = t & 31;
    const int yo = (t >> 5) & 31;
    const int b  = t >> 10;
    const size_t ibase = (size_t)b * NPIX * CC;
    float s = 0.f;
#pragma unroll
    for (int dy = 0; dy < 2; ++dy)
#pragma unroll
      for (int dx = 0; dx < 2; ++dx) {
        const int nin = (2*yo+dy) * 64 + (2*xo+dx);
        const size_t a = ibase + (size_t)nin * CC + swzoff(nin, c);
        s += h2f(in_h[a]) + h2f(in_l[a]);
      }
    const float vv = 0.25f * s;
    const unsigned short hi = f2h(vv);
    const int nout = yo * 32 + xo;
    const size_t ob = ((size_t)b * 1024 + nout) * CC + swzoff(nout, c);
    h2[ob] = hi;
    l2[ob] = f2h(vv - h2f(hi));
    v2[(((size_t)b * 16 + (nout >> 6)) * CC + c) * 64 + swzvslot(nout & 63, c)] =
        f2h(vv);
  } else {                    // ---- pool4: 64x64 -> 16x16 (direct) ----
    const int idx = (bid - 2048) * 256 + threadIdx.x;
    const int c  = idx & 63;
    const int t  = idx >> 6;
    const int xo = t & 15;
    const int yo = (t >> 4) & 15;
    const int b  = t >> 8;
    const size_t ibase = (size_t)b * NPIX * CC;
    float s = 0.f;
#pragma unroll
    for (int dy = 0; dy < 4; ++dy)
#pragma unroll
      for (int dx = 0; dx < 4; ++dx) {
        const int nin = (4*yo+dy) * 64 + (4*xo+dx);
        const size_t a = ibase + (size_t)nin * CC + swzoff(nin, c);
        s += h2f(in_h[a]) + h2f(in_l[a]);
      }
    const float vv = 0.0625f * s;
    const unsigned short hi = f2h(vv);
    const int nout = yo * 16 + xo;
    const size_t ob = ((size_t)b * 256 + nout) * CC + swzoff(nout, c);
    h4[ob] = hi;
    l4[ob] = f2h(vv - h2f(hi));
    v4[(((size_t)b * 4 + (nout >> 6)) * CC + c) * 64 + swzvslot(nout & 63, c)] =
        f2h(vv);
  }
}

// ---------------------------------------------------------------------------
// MFMA flash attention <NH, KS> — round-19 structure (S = Qh·Kh only);
// round 20: pk-cvt P pack + pointer-advance DMA addressing.
// round 21: -Mq folded into QK^T MFMA C-in.
// round 22: launch_bounds back to 4 (5 spilled O/Q to scratch).
// round 23/24: PV tt-pair K=32 merge with bounded live ranges + fence.
// round 25: V-direct-from-global — REVERTED (L2 gather latency + churn).
// round 26: s_setprio — REVERTED (desynced same-XCD block cohort, L2 churn).
// round 28/29/30: VALU->MFMA offload of softmax row-sum. l[q] = P·ones via
// one extra 16x16x32 MFMA per tp per h (C/D layout row=quad*4+reg means
// lacc[h][r] IS the epilogue lq[r], replicated across r16) — kills the
// 7-add lloc chain per h per tp AND the epilogue shuffle reduce. Pf8 built
// by union-bitcast of cvt_pkrtz __fp16x2 pairs. (r30: resubmit — r29 was
// an infra failure, container never ran the kernel.)
// l sums the same fp16-rounded P that feeds PV: exactly-normalized
// weighted average, error ~2^-11 rel, absmax tolerance 0.125.
// ---------------------------------------------------------------------------
template <int NH, int KS>
__device__ __forceinline__ void attn_body(
    int bid,
    const unsigned short* __restrict__ fh,
    const unsigned short* __restrict__ fl,
    const unsigned short* __restrict__ fv,
    float* __restrict__ outF, unsigned short* __restrict__ outB,
    float* __restrict__ outL, int N,
    unsigned short* KVT) {
  const int tid  = threadIdx.x;
  const int lane = tid & 63;
  const int wave = tid >> 6;
  const int b    = bid & 7;              // XCD-local batch grouping
  const int rest = bid >> 3;
  const int nq   = N / (64 * NH);
  const int qt   = rest % nq;
  const int ks   = rest / nq;            // 0..KS-1
  const int q0   = qt * (64 * NH) + wave * (16 * NH);
  const int nt   = (N >> 6) / KS;
  const int t0   = ks * nt;
  const int r16  = lane & 15;
  const int quad = lane >> 4;
  const int swb  = r16 & 7;

  const unsigned short* fhB = fh + (size_t)b * N * CC;   // fp16 K/Q hi
  const unsigned short* flB = fl + (size_t)b * N * CC;   // fp16 Q lo
  const unsigned short* fvB = fv + (size_t)b * N * CC;   // fp16 tile-major V^T

  // ---- per-wave DMA source pointers (advance by 4096 per tile) ----
  const unsigned short* gp[4];
  int ldsoff[4];
#pragma unroll
  for (int j = 0; j < 4; ++j) {
    const int cid = wave * 4 + j;
    const int arr = cid >> 3, sub = (cid & 7) << 9;
    gp[j] = (arr == 0 ? fhB : fvB) + (size_t)t0 * 4096 + sub + lane * 8;
    ldsoff[j] = arr * 4096 + sub + lane * 8;
  }
  // ---- stage first tile ----
#pragma unroll
  for (int j = 0; j < 4; ++j) {
    GLD_LDS16(gp[j], KVT + ldsoff[j]);
    gp[j] += 4096;
  }

  // ---- Q fragments per half: f = h+l (exact M), Qh = fp16(f*log2e) ----
  half8 Qh[NH][2];
  float Mq[NH];
#pragma unroll
  for (int h = 0; h < NH; ++h) {
    float Mpart = 0.f;
#pragma unroll
    for (int kss = 0; kss < 2; ++kss) {
      const size_t off = (size_t)(q0 + h * 16 + r16) * CC
                         + ((((kss << 2) + quad) ^ swb) << 3);
      const ushort8 hh = *(const ushort8*)(fhB + off);
      const ushort8 ll = *(const ushort8*)(flB + off);
      half8 sh;
#pragma unroll
      for (int j = 0; j < 8; ++j) {
        const float f = h2f(hh[j]) + h2f(ll[j]);
        const float g = f * LOG2E;
        sh[j] = (_Float16)g;
        Mpart += g * f;                  // = log2e * sum f^2 (partial)
      }
      Qh[h][kss] = sh;
    }
    Mpart += __shfl_xor(Mpart, 16, 64);
    Mpart += __shfl_xor(Mpart, 32, 64);  // M for q = r16, replicated
    Mq[h] = Mpart;                       // per-lane SCALAR (q = r16)
  }

  // ---- -Mq as an MFMA C-in fragment: QK^T lands pre-shifted ----
  floatx4 nMq[NH];
#pragma unroll
  for (int h = 0; h < NH; ++h)
    nMq[h] = (floatx4){-Mq[h], -Mq[h], -Mq[h], -Mq[h]};

  // ---- all-ones B fragment: l = P * ones via the MFMA pipe ----
  const half8 VONE = {(_Float16)1.f, (_Float16)1.f, (_Float16)1.f,
                      (_Float16)1.f, (_Float16)1.f, (_Float16)1.f,
                      (_Float16)1.f, (_Float16)1.f};

  floatx4 O[NH][4];
  floatx4 lacc[NH];
#pragma unroll
  for (int h = 0; h < NH; ++h) {
    lacc[h] = (floatx4){0.f, 0.f, 0.f, 0.f};
#pragma unroll
    for (int ch = 0; ch < 4; ++ch) O[h][ch] = (floatx4){0.f, 0.f, 0.f, 0.f};
  }

  int koff[2];
#pragma unroll
  for (int kss = 0; kss < 2; ++kss) koff[kss] = (((kss << 2) + quad) ^ swb) << 3;

  for (int t = 0; t < nt; ++t) {
    const int cur = t & 1;
    __syncthreads();                    // drains DMA for tile t, syncs block
    if (t + 1 < nt) {                   // issue DMA for tile t+1 now
      unsigned short* dst = KVT + (cur ^ 1) * 8192;
#pragma unroll
      for (int j = 0; j < 4; ++j) {
        GLD_LDS16(gp[j], dst + ldsoff[j]);
        gp[j] += 4096;
      }
    }
    const unsigned short* kh = KVT + cur * 8192;   // fp16 K hi
    const unsigned short* vt = kh + 4096;          // fp16 V^T

#pragma unroll
    for (int tp = 0; tp < 2; ++tp) {    // tt-pair: keys [tp*32, tp*32+32)
      const int tt0 = tp * 2, tt1 = tp * 2 + 1;
      // ---- S^T for both halves; K fragments transient per scope ----
      floatx4 s0[NH], s1[NH];
      {
        const int kb = (tt0 * 16 + r16) * 64;
        const half8 Ka = *(const half8*)(kh + kb + koff[0]);
        const half8 Kb = *(const half8*)(kh + kb + koff[1]);
#pragma unroll
        for (int h = 0; h < NH; ++h) {
          s0[h] = __builtin_amdgcn_mfma_f32_16x16x32_f16(Ka, Qh[h][0], nMq[h], 0, 0, 0);
          s0[h] = __builtin_amdgcn_mfma_f32_16x16x32_f16(Kb, Qh[h][1], s0[h], 0, 0, 0);
        }
      }
      {
        const int kb = (tt1 * 16 + r16) * 64;
        const half8 Ka = *(const half8*)(kh + kb + koff[0]);
        const half8 Kb = *(const half8*)(kh + kb + koff[1]);
#pragma unroll
        for (int h = 0; h < NH; ++h) {
          s1[h] = __builtin_amdgcn_mfma_f32_16x16x32_f16(Ka, Qh[h][0], nMq[h], 0, 0, 0);
          s1[h] = __builtin_amdgcn_mfma_f32_16x16x32_f16(Kb, Qh[h][1], s1[h], 0, 0, 0);
        }
      }
      // ---- fixed-shift softmax; P packed via cvt_pkrtz union bitcast ----
      half8 Pf8[NH];
#pragma unroll
      for (int h = 0; h < NH; ++h) {
        const float p0 = __builtin_amdgcn_exp2f(s0[h][0]);
        const float p1 = __builtin_amdgcn_exp2f(s0[h][1]);
        const float p2 = __builtin_amdgcn_exp2f(s0[h][2]);
        const float p3 = __builtin_amdgcn_exp2f(s0[h][3]);
        const float p4 = __builtin_amdgcn_exp2f(s1[h][0]);
        const float p5 = __builtin_amdgcn_exp2f(s1[h][1]);
        const float p6 = __builtin_amdgcn_exp2f(s1[h][2]);
        const float p7 = __builtin_amdgcn_exp2f(s1[h][3]);
        union { half8 v; fp16x2 h2[4]; } u;
        u.h2[0] = __builtin_amdgcn_cvt_pkrtz(p0, p1);
        u.h2[1] = __builtin_amdgcn_cvt_pkrtz(p2, p3);
        u.h2[2] = __builtin_amdgcn_cvt_pkrtz(p4, p5);
        u.h2[3] = __builtin_amdgcn_cvt_pkrtz(p6, p7);
        Pf8[h] = u.v;
      }
      // Pressure fence: V loads + addressing may NOT hoist above this point.
      __builtin_amdgcn_sched_barrier(0);
      // ---- PV: per-ch V pair load, consumed immediately ----
      const int vs0 = (((tt0 * 4 + quad) ^ r16) << 2);
      const int vs1 = (((tt1 * 4 + quad) ^ r16) << 2);
#pragma unroll
      for (int ch = 0; ch < 4; ++ch) {
        const half4 va = *(const half4*)(vt + (ch * 16 + r16) * 64 + vs0);
        const half4 vb = *(const half4*)(vt + (ch * 16 + r16) * 64 + vs1);
        const half8 Vf8 = (half8){va[0], va[1], va[2], va[3],
                                  vb[0], vb[1], vb[2], vb[3]};
#pragma unroll
        for (int h = 0; h < NH; ++h)
          O[h][ch] = __builtin_amdgcn_mfma_f32_16x16x32_f16(Pf8[h], Vf8,
                                                            O[h][ch], 0, 0, 0);
      }
      // ---- l += P * ones on the MFMA pipe (replaces 7-add VALU chain) ----
#pragma unroll
      for (int h = 0; h < NH; ++h)
        lacc[h] = __builtin_amdgcn_mfma_f32_16x16x32_f16(Pf8[h], VONE,
                                                         lacc[h], 0, 0, 0);
    }
  }

  // ---- epilogue: lacc[h][r] = l for q=quad*4+r (replicated over r16) ----
#pragma unroll
  for (int h = 0; h < NH; ++h) {
    if (KS != 1 && r16 == 0) {
#pragma unroll
      for (int r = 0; r < 4; ++r)
        outL[(size_t)ks * BB * N + (size_t)b * N + q0 + h * 16 + quad * 4 + r] =
            lacc[h][r];
    }
#pragma unroll
    for (int ch = 0; ch < 4; ++ch)
#pragma unroll
      for (int r = 0; r < 4; ++r) {
        const size_t qi = (size_t)b * N + q0 + h * 16 + quad * 4 + r;
        if (KS == 1) {
          outF[qi * CC + ch * 16 + r16] = O[h][ch][r] / lacc[h][r];
        } else {
          outB[(size_t)ks * BB * N * CC + qi * CC + ch * 16 + r16] =
              f2bf_fast(O[h][ch][r]);
        }
      }
  }
}

// Merged dispatch — short blocks first (tail-fill), segment offsets ≡0 mod 8
// so b = bid&7 XCD grouping is preserved.
// [0,256) scale-2 NH=1/KS=2; [256,288) scale-4 NH=1/KS=1;
// [288,1312) scale-1 NH=2/KS=4. LDS 32KB -> 4 blocks/CU (VGPR cap 128).
__global__ __launch_bounds__(256, 4) void attn_all(
    const unsigned short* __restrict__ fh1, const unsigned short* __restrict__ fl1,
    const unsigned short* __restrict__ fv1,
    unsigned short* __restrict__ Op1, float* __restrict__ Lp1,
    const unsigned short* __restrict__ fh2, const unsigned short* __restrict__ fl2,
    const unsigned short* __restrict__ fv2,
    unsigned short* __restrict__ Op2, float* __restrict__ Lp2,
    const unsigned short* __restrict__ fh4, const unsigned short* __restrict__ fl4,
    const unsigned short* __restrict__ fv4, float* __restrict__ a4) {
  __shared__ __align__(16) unsigned short KVT[2][2 * 4096];
  const int bid = blockIdx.x;
  if (bid < 256) {
    attn_body<1, 2>(bid, fh2, fl2, fv2, nullptr, Op2, Lp2, 1024, &KVT[0][0]);
  } else if (bid < 288) {
    attn_body<1, 1>(bid - 256, fh4, fl4, fv4, a4, nullptr, nullptr, 256,
                    &KVT[0][0]);
  } else {
    attn_body<2, 4>(bid - 288, fh1, fl1, fv1, nullptr, Op1, Lp1, NPIX,
                    &KVT[0][0]);
  }
}

// ---------------------------------------------------------------------------
// final3: FUSED scale-1 combine (4 partials) + scale-2 combine (2 partials)
// + output assembly. Block = (b, y-row). (unchanged)
// ---------------------------------------------------------------------------
__global__ __launch_bounds__(256) void final3_kernel(
    const float* __restrict__ xin,
    const unsigned short* __restrict__ Op1, const float* __restrict__ Lp1,
    const unsigned short* __restrict__ Op2, const float* __restrict__ Lp2,
    const float* __restrict__ a4, float* __restrict__ out) {
  __shared__ float T[64][65];
  __shared__ float T2[64][66];
  const int tid = threadIdx.x;
  const int y = blockIdx.x & 63;
  const int b = blockIdx.x >> 6;
  const size_t S1 = (size_t)BB * NPIX * CC;
  const size_t T1 = (size_t)BB * NPIX;
  const size_t S2 = (size_t)BB * 1024 * CC;
  const size_t L2 = (size_t)BB * 1024;

  const float ty2 = y * 0.5f - 0.25f;
  const int iy2 = (int)floorf(ty2);
  const float wy2 = ty2 - iy2;
  const int iy20 = max(iy2, 0), iy21 = min(iy2 + 1, 31);

  const int nl = tid >> 2;             // 0..63
  const int ck = (tid & 3) * 16;       // c chunk

  {  // ---- phase 1: combine scale-1 row y (4 partials) ----
    const int n = y * 64 + nl;
    float lv = 0.f;
#pragma unroll
    for (int ks = 0; ks < 4; ++ks)
      lv += Lp1[(size_t)ks * T1 + (size_t)b * NPIX + n];
    const float inv = 1.f / lv;
    float v[16];
#pragma unroll
    for (int j = 0; j < 16; ++j) v[j] = 0.f;
#pragma unroll
    for (int ks = 0; ks < 4; ++ks) {
      const unsigned short* src =
          Op1 + (size_t)ks * S1 + ((size_t)b * NPIX + n) * CC + ck;
      const ushort8 u0 = *(const ushort8*)(src);
      const ushort8 u1 = *(const ushort8*)(src + 8);
#pragma unroll
      for (int j = 0; j < 8; ++j) {
        v[j]     += bf2f(u0[j]);
        v[8 + j] += bf2f(u1[j]);
      }
    }
#pragma unroll
    for (int j = 0; j < 16; ++j) T[ck + j][nl] = v[j] * inv;
  }
  {  // ---- phase 1b: combine scale-2 rows iy20 (nl<32) / iy21 (nl>=32) ----
    const int row = nl >> 5;
    const int ix  = nl & 31;
    const int n2  = (row == 0 ? iy20 : iy21) * 32 + ix;
    float lv = Lp2[(size_t)b * 1024 + n2] + Lp2[L2 + (size_t)b * 1024 + n2];
    const float inv = 1.f / lv;
    float v[16];
#pragma unroll
    for (int j = 0; j < 16; ++j) v[j] = 0.f;
#pragma unroll
    for (int ks = 0; ks < 2; ++ks) {
      const unsigned short* src =
          Op2 + (size_t)ks * S2 + ((size_t)b * 1024 + n2) * CC + ck;
      const ushort8 u0 = *(const ushort8*)(src);
      const ushort8 u1 = *(const ushort8*)(src + 8);
#pragma unroll
      for (int j = 0; j < 8; ++j) {
        v[j]     += bf2f(u0[j]);
        v[8 + j] += bf2f(u1[j]);
      }
    }
#pragma unroll
    for (int j = 0; j < 16; ++j) T2[ck + j][nl] = v[j] * inv;
  }
  __syncthreads();

  // ---- phase 2: assemble output row ----
  const int c  = tid >> 2;
  const int xk = (tid & 3) * 16;
  const float* xrow = xin + (((size_t)b * CC + c) * HH + y) * WW;
  float* orow = out + (((size_t)b * CC + c) * HH + y) * WW;

  const float ty4 = y * 0.25f - 0.375f;
  const int iy4 = (int)floorf(ty4);
  const float wy4 = ty4 - iy4;
  const int iy40 = max(iy4, 0), iy41 = min(iy4 + 1, 15);
  const float* b4 = a4 + (size_t)b * 256 * 64 + c;

#pragma unroll
  for (int j = 0; j < 16; ++j) {
    const int xx = xk + j;
    float r = xrow[xx] + T[c][xx];
    {  // scale 2 (rows pre-combined in T2: cols 0-31 = iy20, 32-63 = iy21)
      const float tx = xx * 0.5f - 0.25f;
      const int ix = (int)floorf(tx);
      const float wx = tx - ix;
      const int ix0 = max(ix, 0), ix1 = min(ix + 1, 31);
      const float v00 = T2[c][ix0],      v01 = T2[c][ix1];
      const float v10 = T2[c][32 + ix0], v11 = T2[c][32 + ix1];
      r += (1.f-wy2)*((1.f-wx)*v00 + wx*v01) + wy2*((1.f-wx)*v10 + wx*v11);
    }
    {  // scale 4
      const float tx = xx * 0.25f - 0.375f;
      const int ix = (int)floorf(tx);
      const float wx = tx - ix;
      const int ix0 = max(ix, 0), ix1 = min(ix + 1, 15);
      const float v00 = b4[(iy40*16+ix0)*64], v01 = b4[(iy40*16+ix1)*64];
      const float v10 = b4[(iy41*16+ix0)*64], v11 = b4[(iy41*16+ix1)*64];
      r += (1.f-wy4)*((1.f-wx)*v00 + wx*v01) + wy4*((1.f-wx)*v10 + wx*v11);
    }
    orow[xx] = r;
  }
}

// ---------------------------------------------------------------------------
extern "C" void kernel_launch(void* const* d_in, const int* in_sizes, int n_in,
                              void* d_out, int out_size, void* d_ws,
                              size_t ws_size, hipStream_t stream) {
  const float* x = (const float*)d_in[0];
  const float* w = (const float*)d_in[1];
  float* out = (float*)d_out;

  unsigned short* fh1 = (unsigned short*)d_ws;            // [8][4096][64] fp16 swz
  unsigned short* fl1 = fh1 + (size_t)BB*NPIX*CC;         // fp16 lo
  unsigned short* fv1 = fl1 + (size_t)BB*NPIX*CC;         // fp16 tile-major V^T
  unsigned short* fh2 = fv1 + (size_t)BB*NPIX*CC;         // [8][1024][64]
  unsigned short* fl2 = fh2 + (size_t)BB*1024*CC;
  unsigned short* fv2 = fl2 + (size_t)BB*1024*CC;
  unsigned short* fh4 = fv2 + (size_t)BB*1024*CC;         // [8][256][64]
  unsigned short* fl4 = fh4 + (size_t)BB*256*CC;
  unsigned short* fv4 = fl4 + (size_t)BB*256*CC;
  unsigned short* Op1 = fv4 + (size_t)BB*256*CC;          // [4][8][4096][64] bf16
  float* Lp1 = (float*)(Op1 + 4*(size_t)BB*NPIX*CC);      // [4][8][4096]
  unsigned short* Op2 = (unsigned short*)(Lp1 + 4*(size_t)BB*NPIX);  // [2][8][1024][64]
  float* Lp2 = (float*)(Op2 + 2*(size_t)BB*1024*CC);      // [2][8][1024]
  float* a4  = Lp2 + 2*(size_t)BB*1024;                   // [8][256][64] fp32

  // Dead-time aliases: WT (dead after conv_mfma) aliases Op2 (attn later)
  unsigned short* wth = (unsigned short*)Op2;             // 72 KB
  unsigned short* wtl = wth + 9*64*64;                    // 72 KB

  wprep_kernel<<<144, 256, 0, stream>>>(w, wth, wtl);
  conv_mfma<<<dim3(64, 8), 256, 0, stream>>>(x, wth, wtl, fh1, fl1, fv1);
  pools_kernel<<<2560, 256, 0, stream>>>(fh1, fl1, fh2, fl2, fv2, fh4, fl4, fv4);
  attn_all<<<1312, 256, 0, stream>>>(fh1, fl1, fv1, Op1, Lp1,
                                     fh2, fl2, fv2, Op2, Lp2,
                                     fh4, fl4, fv4, a4);
  final3_kernel<<<512, 256, 0, stream>>>(x, Op1, Lp1, Op2, Lp2, a4, out);
}

// Round 11
// 136.188 us; speedup vs baseline: 1.3088x; 1.0032x over previous
//
#include <hip/hip_runtime.h>
#include <hip/hip_bf16.h>
#include <math.h>

// Problem constants: x [8,64,64,64] fp32 NCHW, W_std [64,64,3,3] fp32 OIHW.
#define BB 8
#define CC 64
#define HH 64
#define WW 64
#define NPIX (HH*WW)   // 4096
#define LOG2E 1.44269504088896340736f

typedef __attribute__((ext_vector_type(8))) short bf16x8;            // bf16 A/B frag
typedef __attribute__((ext_vector_type(8))) _Float16 half8;          // fp16 A/B frag (K=32)
typedef __attribute__((ext_vector_type(4))) _Float16 half4;          // fp16 A/B frag (K=16)
typedef __attribute__((ext_vector_type(2))) __fp16 fp16x2;           // cvt_pkrtz result
typedef __attribute__((ext_vector_type(4))) float floatx4;           // MFMA C/D frag
typedef __attribute__((ext_vector_type(8))) unsigned short ushort8;  // 16B unit

__device__ inline unsigned short f2bf(float x) {
  __hip_bfloat16 h = __float2bfloat16(x);
  return *reinterpret_cast<unsigned short*>(&h);
}
__device__ inline unsigned short f2bf_fast(float x) {
  const unsigned u = __float_as_uint(x);
  return (unsigned short)((u + 0x8000u) >> 16);
}
__device__ inline float bf2f(unsigned short u) {
  __hip_bfloat16 h = *reinterpret_cast<__hip_bfloat16*>(&u);
  return __bfloat162float(h);
}
__device__ inline unsigned short f2h(float x) {
  _Float16 h = (_Float16)x;
  return *reinterpret_cast<unsigned short*>(&h);
}
__device__ inline float h2f(unsigned short u) {
  _Float16 h = *reinterpret_cast<_Float16*>(&u);
  return (float)h;
}

// XOR swizzle for K/Q rows: 16B chunks permuted within each 128B row.
__device__ inline int swzoff(int n, int c) {
  return (((c >> 3) ^ (n & 7)) << 3) | (c & 7);
}
// V^T swizzle: b64-granular (round 18 — measured 4.75M -> 0 conflicts).
__device__ inline int swzvslot(int key, int c) {
  return ((((key >> 2) ^ (c & 15)) << 2)) | (key & 3);
}

// 16B global -> LDS DMA (per-lane global scatter OK; LDS dest = base+lane*16)
#define GLD_LDS16(gp, lp)                                                     \
  __builtin_amdgcn_global_load_lds(                                           \
      (const __attribute__((address_space(1))) void*)(gp),                    \
      (__attribute__((address_space(3))) void*)(lp), 16, 0, 0)

// ---------------------------------------------------------------------------
// wprep: WT[tap][o][c] bf16 hi/lo, depthwise Laplacian folded in.
// ---------------------------------------------------------------------------
__global__ __launch_bounds__(256) void wprep_kernel(
    const float* __restrict__ w,
    unsigned short* __restrict__ wth, unsigned short* __restrict__ wtl) {
  const int idx = blockIdx.x * 256 + threadIdx.x;   // 9*64*64 = 36864
  const int c   = idx & 63;
  const int o   = (idx >> 6) & 63;
  const int tap = idx >> 12;
  float v = w[((o * 64 + c) * 9) + tap];
  if (o == c) {
    const float lapk[9] = {0.f, 1.f, 0.f, 1.f, -4.f, 1.f, 0.f, 1.f, 0.f};
    v += lapk[tap];
  }
  const unsigned short hi = f2bf(v);
  wth[(tap * 64 + o) * 64 + c] = hi;
  wtl[(tap * 64 + o) * 64 + c] = f2bf(v - bf2f(hi));
}

// ---------------------------------------------------------------------------
// conv_mfma: implicit-GEMM conv. Round 20: SINGLE-PHASE staging — DMA all
// 3 fp32 x-rows (48KB) into the XS region itself, drain ONCE, copy each
// thread's 48 values to registers, barrier, convert/write the swizzled
// bf16 hi/lo layout in place. 6 barriers -> 3, XLf gone, LDS 64 -> 48KB
// -> 3 blocks/CU.
// ---------------------------------------------------------------------------
__global__ __launch_bounds__(256, 3) void conv_mfma(
    const float* __restrict__ xin,
    const unsigned short* __restrict__ wth,
    const unsigned short* __restrict__ wtl,
    unsigned short* __restrict__ fh, unsigned short* __restrict__ fl,
    unsigned short* __restrict__ fv) {
  __shared__ __align__(16) unsigned short XS[6 * 4096];  // 48KB

  const int tid  = threadIdx.x;
  const int lane = tid & 63;
  const int wave = tid >> 6;
  const int r16  = lane & 15;
  const int quad = lane >> 4;
  const int y = blockIdx.x, b = blockIdx.y;
  const int px = tid & 63, cp = tid >> 6;

  // ---- stage: DMA 3 rows fp32 [c][x] into XS bytes [r*16KB ...] ----
  float* XSf = (float*)XS;
  const float* xb = xin + (size_t)b * CC * NPIX;
#pragma unroll
  for (int r = 0; r < 3; ++r) {
    const int yy = min(max(y - 1 + r, 0), HH - 1);
    const float* xrow = xb + yy * WW;
#pragma unroll
    for (int j = 0; j < 4; ++j) {
      const int cb = (wave * 4 + j) * 4;        // 4 channel-rows per DMA
      const int cl = cb + (lane >> 4);
      const float* g = xrow + (size_t)cl * NPIX + ((lane & 15) << 2);
      GLD_LDS16(g, (char*)XSf + r * 16384 + cb * 256 + lane * 16);
    }
  }
  __syncthreads();                              // single DMA drain

  // ---- copy this thread's 48 values to regs (fp32 region dies next) ----
  float xv[3][16];
#pragma unroll
  for (int r = 0; r < 3; ++r)
#pragma unroll
    for (int j = 0; j < 16; ++j)
      xv[r][j] = XSf[r * 4096 + (cp * 16 + j) * 64 + px];
  __syncthreads();                              // all reads done

  // ---- convert/write swizzled bf16 hi/lo in place ----
#pragma unroll
  for (int r = 0; r < 3; ++r) {
    ushort8 vh[2], vl[2];
#pragma unroll
    for (int j = 0; j < 16; ++j) {
      const float v = xv[r][j];
      const unsigned short hh = f2bf(v);
      vh[j >> 3][j & 7] = hh;
      vl[j >> 3][j & 7] = f2bf(v - bf2f(hh));
    }
    unsigned short* xsh = XS + r * 4096 + px * 64;
    unsigned short* xsl = XS + (3 + r) * 4096 + px * 64;
#pragma unroll
    for (int k = 0; k < 2; ++k) {
      const int ch = cp * 2 + k;
      const int off = ((ch ^ (px & 7)) << 3);
      *(ushort8*)(xsh + off) = vh[k];
      *(ushort8*)(xsl + off) = vl[k];
    }
  }
  __syncthreads();                              // XS ready

  floatx4 acc[4];
#pragma unroll
  for (int t = 0; t < 4; ++t) acc[t] = (floatx4){0.f, 0.f, 0.f, 0.f};
  const bf16x8 ZF = {0, 0, 0, 0, 0, 0, 0, 0};
  const int og = wave * 16 + r16;

#pragma unroll
  for (int tap = 0; tap < 9; ++tap) {
    const int ky = tap / 3, kx = tap % 3;
    const int yy = y + ky - 1;
    if (yy < 0 || yy >= HH) continue;
    const unsigned short* wt = wth + ((tap * 64 + og) << 6);
    const unsigned short* wl = wtl + ((tap * 64 + og) << 6);
    const bf16x8 Wh0 = *(const bf16x8*)(wt + quad * 8);
    const bf16x8 Wh1 = *(const bf16x8*)(wt + 32 + quad * 8);
    const bf16x8 Wl0 = *(const bf16x8*)(wl + quad * 8);
    const bf16x8 Wl1 = *(const bf16x8*)(wl + 32 + quad * 8);
#pragma unroll
    for (int t = 0; t < 4; ++t) {
      const int px2 = t * 16 + r16 + kx - 1;
      const bool ok = (px2 >= 0) && (px2 < WW);
      const int pxc = ok ? px2 : 0;
      const int bh = ky * 4096 + pxc * 64;
      const int bl = bh + 3 * 4096;
      const int o0 = ((quad ^ (pxc & 7)) << 3);
      const int o1 = (((4 + quad) ^ (pxc & 7)) << 3);
      bf16x8 Ah0 = *(const bf16x8*)(XS + bh + o0);
      bf16x8 Ah1 = *(const bf16x8*)(XS + bh + o1);
      bf16x8 Al0 = *(const bf16x8*)(XS + bl + o0);
      bf16x8 Al1 = *(const bf16x8*)(XS + bl + o1);
      if (!ok) { Ah0 = ZF; Ah1 = ZF; Al0 = ZF; Al1 = ZF; }
      acc[t] = __builtin_amdgcn_mfma_f32_16x16x32_bf16(Ah0, Wh0, acc[t], 0, 0, 0);
      acc[t] = __builtin_amdgcn_mfma_f32_16x16x32_bf16(Ah1, Wh1, acc[t], 0, 0, 0);
      acc[t] = __builtin_amdgcn_mfma_f32_16x16x32_bf16(Ah0, Wl0, acc[t], 0, 0, 0);
      acc[t] = __builtin_amdgcn_mfma_f32_16x16x32_bf16(Ah1, Wl1, acc[t], 0, 0, 0);
      acc[t] = __builtin_amdgcn_mfma_f32_16x16x32_bf16(Al0, Wh0, acc[t], 0, 0, 0);
      acc[t] = __builtin_amdgcn_mfma_f32_16x16x32_bf16(Al1, Wh1, acc[t], 0, 0, 0);
    }
  }

#pragma unroll
  for (int t = 0; t < 4; ++t)
#pragma unroll
    for (int r = 0; r < 4; ++r) {
      const int key = t * 16 + quad * 4 + r;
      const int n = y * WW + key;
      const float v = acc[t][r];
      const unsigned short hi = f2h(v);               // fp16 hi
      const unsigned short lo = f2h(v - h2f(hi));     // fp16 lo
      fh[((size_t)b * NPIX + n) * CC + swzoff(n, og)] = hi;
      fl[((size_t)b * NPIX + n) * CC + swzoff(n, og)] = lo;
      fv[(((size_t)b * (NPIX >> 6) + y) * CC + og) * 64 + swzvslot(key, og)] =
          f2h(v);                                     // V^T fp16
    }
}

// ---------------------------------------------------------------------------
// pools: merged pool2 + pool4-direct (unchanged).
// ---------------------------------------------------------------------------
__global__ void pools_kernel(const unsigned short* __restrict__ in_h,
                             const unsigned short* __restrict__ in_l,
                             unsigned short* __restrict__ h2,
                             unsigned short* __restrict__ l2,
                             unsigned short* __restrict__ v2,
                             unsigned short* __restrict__ h4,
                             unsigned short* __restrict__ l4,
                             unsigned short* __restrict__ v4) {
  const int bid = blockIdx.x;
  if (bid < 2048) {           // ---- pool2: 64x64 -> 32x32 ----
    const int idx = bid * 256 + threadIdx.x;
    const int c  = idx & 63;
    const int t  = idx >> 6;
    const int xo = t & 31;
    const int yo = (t >> 5) & 31;
    const int b  = t >> 10;
    const size_t ibase = (size_t)b * NPIX * CC;
    float s = 0.f;
#pragma unroll
    for (int dy = 0; dy < 2; ++dy)
#pragma unroll
      for (int dx = 0; dx < 2; ++dx) {
        const int nin = (2*yo+dy) * 64 + (2*xo+dx);
        const size_t a = ibase + (size_t)nin * CC + swzoff(nin, c);
        s += h2f(in_h[a]) + h2f(in_l[a]);
      }
    const float vv = 0.25f * s;
    const unsigned short hi = f2h(vv);
    const int nout = yo * 32 + xo;
    const size_t ob = ((size_t)b * 1024 + nout) * CC + swzoff(nout, c);
    h2[ob] = hi;
    l2[ob] = f2h(vv - h2f(hi));
    v2[(((size_t)b * 16 + (nout >> 6)) * CC + c) * 64 + swzvslot(nout & 63, c)] =
        f2h(vv);
  } else {                    // ---- pool4: 64x64 -> 16x16 (direct) ----
    const int idx = (bid - 2048) * 256 + threadIdx.x;
    const int c  = idx & 63;
    const int t  = idx >> 6;
    const int xo = t & 15;
    const int yo = (t >> 4) & 15;
    const int b  = t >> 8;
    const size_t ibase = (size_t)b * NPIX * CC;
    float s = 0.f;
#pragma unroll
    for (int dy = 0; dy < 4; ++dy)
#pragma unroll
      for (int dx = 0; dx < 4; ++dx) {
        const int nin = (4*yo+dy) * 64 + (4*xo+dx);
        const size_t a = ibase + (size_t)nin * CC + swzoff(nin, c);
        s += h2f(in_h[a]) + h2f(in_l[a]);
      }
    const float vv = 0.0625f * s;
    const unsigned short hi = f2h(vv);
    const int nout = yo * 16 + xo;
    const size_t ob = ((size_t)b * 256 + nout) * CC + swzoff(nout, c);
    h4[ob] = hi;
    l4[ob] = f2h(vv - h2f(hi));
    v4[(((size_t)b * 4 + (nout >> 6)) * CC + c) * 64 + swzvslot(nout & 63, c)] =
        f2h(vv);
  }
}

// ---------------------------------------------------------------------------
// MFMA flash attention <NH, KS> — round-19 structure (S = Qh·Kh only);
// round 20: pk-cvt P pack + pointer-advance DMA addressing.
// round 21: -Mq folded into QK^T MFMA C-in.
// round 22: launch_bounds back to 4 (5 spilled O/Q to scratch).
// round 23/24: PV tt-pair K=32 merge with bounded live ranges + fence.
// round 25: V-direct-from-global — REVERTED (L2 gather latency + churn).
// round 26: s_setprio — REVERTED (desynced same-XCD block cohort, L2 churn).
// round 30: softmax row-sum on the MFMA pipe (l = P·ones, lacc[h][r] is the
// epilogue lq[r] directly) + Pf8 union-bitcast pack. attn 48.4->47.2,
// VGPR 64->60, VALUBusy 46->42.7. WORKS.
// round 31: Vf8 union-coalesce — build the PV A-operand via
// union{half8; half4[2]} member assignment instead of element-wise concat,
// giving regalloc an explicit pair-coalescing contract (kills up to 16
// v_mov per tp if the loads weren't landing adjacent).
// ---------------------------------------------------------------------------
template <int NH, int KS>
__device__ __forceinline__ void attn_body(
    int bid,
    const unsigned short* __restrict__ fh,
    const unsigned short* __restrict__ fl,
    const unsigned short* __restrict__ fv,
    float* __restrict__ outF, unsigned short* __restrict__ outB,
    float* __restrict__ outL, int N,
    unsigned short* KVT) {
  const int tid  = threadIdx.x;
  const int lane = tid & 63;
  const int wave = tid >> 6;
  const int b    = bid & 7;              // XCD-local batch grouping
  const int rest = bid >> 3;
  const int nq   = N / (64 * NH);
  const int qt   = rest % nq;
  const int ks   = rest / nq;            // 0..KS-1
  const int q0   = qt * (64 * NH) + wave * (16 * NH);
  const int nt   = (N >> 6) / KS;
  const int t0   = ks * nt;
  const int r16  = lane & 15;
  const int quad = lane >> 4;
  const int swb  = r16 & 7;

  const unsigned short* fhB = fh + (size_t)b * N * CC;   // fp16 K/Q hi
  const unsigned short* flB = fl + (size_t)b * N * CC;   // fp16 Q lo
  const unsigned short* fvB = fv + (size_t)b * N * CC;   // fp16 tile-major V^T

  // ---- per-wave DMA source pointers (advance by 4096 per tile) ----
  const unsigned short* gp[4];
  int ldsoff[4];
#pragma unroll
  for (int j = 0; j < 4; ++j) {
    const int cid = wave * 4 + j;
    const int arr = cid >> 3, sub = (cid & 7) << 9;
    gp[j] = (arr == 0 ? fhB : fvB) + (size_t)t0 * 4096 + sub + lane * 8;
    ldsoff[j] = arr * 4096 + sub + lane * 8;
  }
  // ---- stage first tile ----
#pragma unroll
  for (int j = 0; j < 4; ++j) {
    GLD_LDS16(gp[j], KVT + ldsoff[j]);
    gp[j] += 4096;
  }

  // ---- Q fragments per half: f = h+l (exact M), Qh = fp16(f*log2e) ----
  half8 Qh[NH][2];
  float Mq[NH];
#pragma unroll
  for (int h = 0; h < NH; ++h) {
    float Mpart = 0.f;
#pragma unroll
    for (int kss = 0; kss < 2; ++kss) {
      const size_t off = (size_t)(q0 + h * 16 + r16) * CC
                         + ((((kss << 2) + quad) ^ swb) << 3);
      const ushort8 hh = *(const ushort8*)(fhB + off);
      const ushort8 ll = *(const ushort8*)(flB + off);
      half8 sh;
#pragma unroll
      for (int j = 0; j < 8; ++j) {
        const float f = h2f(hh[j]) + h2f(ll[j]);
        const float g = f * LOG2E;
        sh[j] = (_Float16)g;
        Mpart += g * f;                  // = log2e * sum f^2 (partial)
      }
      Qh[h][kss] = sh;
    }
    Mpart += __shfl_xor(Mpart, 16, 64);
    Mpart += __shfl_xor(Mpart, 32, 64);  // M for q = r16, replicated
    Mq[h] = Mpart;                       // per-lane SCALAR (q = r16)
  }

  // ---- -Mq as an MFMA C-in fragment: QK^T lands pre-shifted ----
  floatx4 nMq[NH];
#pragma unroll
  for (int h = 0; h < NH; ++h)
    nMq[h] = (floatx4){-Mq[h], -Mq[h], -Mq[h], -Mq[h]};

  // ---- all-ones B fragment: l = P * ones via the MFMA pipe ----
  const half8 VONE = {(_Float16)1.f, (_Float16)1.f, (_Float16)1.f,
                      (_Float16)1.f, (_Float16)1.f, (_Float16)1.f,
                      (_Float16)1.f, (_Float16)1.f};

  floatx4 O[NH][4];
  floatx4 lacc[NH];
#pragma unroll
  for (int h = 0; h < NH; ++h) {
    lacc[h] = (floatx4){0.f, 0.f, 0.f, 0.f};
#pragma unroll
    for (int ch = 0; ch < 4; ++ch) O[h][ch] = (floatx4){0.f, 0.f, 0.f, 0.f};
  }

  int koff[2];
#pragma unroll
  for (int kss = 0; kss < 2; ++kss) koff[kss] = (((kss << 2) + quad) ^ swb) << 3;

  for (int t = 0; t < nt; ++t) {
    const int cur = t & 1;
    __syncthreads();                    // drains DMA for tile t, syncs block
    if (t + 1 < nt) {                   // issue DMA for tile t+1 now
      unsigned short* dst = KVT + (cur ^ 1) * 8192;
#pragma unroll
      for (int j = 0; j < 4; ++j) {
        GLD_LDS16(gp[j], dst + ldsoff[j]);
        gp[j] += 4096;
      }
    }
    const unsigned short* kh = KVT + cur * 8192;   // fp16 K hi
    const unsigned short* vt = kh + 4096;          // fp16 V^T

#pragma unroll
    for (int tp = 0; tp < 2; ++tp) {    // tt-pair: keys [tp*32, tp*32+32)
      const int tt0 = tp * 2, tt1 = tp * 2 + 1;
      // ---- S^T for both halves; K fragments transient per scope ----
      floatx4 s0[NH], s1[NH];
      {
        const int kb = (tt0 * 16 + r16) * 64;
        const half8 Ka = *(const half8*)(kh + kb + koff[0]);
        const half8 Kb = *(const half8*)(kh + kb + koff[1]);
#pragma unroll
        for (int h = 0; h < NH; ++h) {
          s0[h] = __builtin_amdgcn_mfma_f32_16x16x32_f16(Ka, Qh[h][0], nMq[h], 0, 0, 0);
          s0[h] = __builtin_amdgcn_mfma_f32_16x16x32_f16(Kb, Qh[h][1], s0[h], 0, 0, 0);
        }
      }
      {
        const int kb = (tt1 * 16 + r16) * 64;
        const half8 Ka = *(const half8*)(kh + kb + koff[0]);
        const half8 Kb = *(const half8*)(kh + kb + koff[1]);
#pragma unroll
        for (int h = 0; h < NH; ++h) {
          s1[h] = __builtin_amdgcn_mfma_f32_16x16x32_f16(Ka, Qh[h][0], nMq[h], 0, 0, 0);
          s1[h] = __builtin_amdgcn_mfma_f32_16x16x32_f16(Kb, Qh[h][1], s1[h], 0, 0, 0);
        }
      }
      // ---- fixed-shift softmax; P packed via cvt_pkrtz union bitcast ----
      half8 Pf8[NH];
#pragma unroll
      for (int h = 0; h < NH; ++h) {
        const float p0 = __builtin_amdgcn_exp2f(s0[h][0]);
        const float p1 = __builtin_amdgcn_exp2f(s0[h][1]);
        const float p2 = __builtin_amdgcn_exp2f(s0[h][2]);
        const float p3 = __builtin_amdgcn_exp2f(s0[h][3]);
        const float p4 = __builtin_amdgcn_exp2f(s1[h][0]);
        const float p5 = __builtin_amdgcn_exp2f(s1[h][1]);
        const float p6 = __builtin_amdgcn_exp2f(s1[h][2]);
        const float p7 = __builtin_amdgcn_exp2f(s1[h][3]);
        union { half8 v; fp16x2 h2[4]; } u;
        u.h2[0] = __builtin_amdgcn_cvt_pkrtz(p0, p1);
        u.h2[1] = __builtin_amdgcn_cvt_pkrtz(p2, p3);
        u.h2[2] = __builtin_amdgcn_cvt_pkrtz(p4, p5);
        u.h2[3] = __builtin_amdgcn_cvt_pkrtz(p6, p7);
        Pf8[h] = u.v;
      }
      // Pressure fence: V loads + addressing may NOT hoist above this point.
      __builtin_amdgcn_sched_barrier(0);
      // ---- PV: per-ch V pair load, union-coalesced, consumed immediately ----
      const int vs0 = (((tt0 * 4 + quad) ^ r16) << 2);
      const int vs1 = (((tt1 * 4 + quad) ^ r16) << 2);
#pragma unroll
      for (int ch = 0; ch < 4; ++ch) {
        union { half8 v; half4 h4[2]; } uv;
        uv.h4[0] = *(const half4*)(vt + (ch * 16 + r16) * 64 + vs0);
        uv.h4[1] = *(const half4*)(vt + (ch * 16 + r16) * 64 + vs1);
        const half8 Vf8 = uv.v;
#pragma unroll
        for (int h = 0; h < NH; ++h)
          O[h][ch] = __builtin_amdgcn_mfma_f32_16x16x32_f16(Pf8[h], Vf8,
                                                            O[h][ch], 0, 0, 0);
      }
      // ---- l += P * ones on the MFMA pipe (replaces 7-add VALU chain) ----
#pragma unroll
      for (int h = 0; h < NH; ++h)
        lacc[h] = __builtin_amdgcn_mfma_f32_16x16x32_f16(Pf8[h], VONE,
                                                         lacc[h], 0, 0, 0);
    }
  }

  // ---- epilogue: lacc[h][r] = l for q=quad*4+r (replicated over r16) ----
#pragma unroll
  for (int h = 0; h < NH; ++h) {
    if (KS != 1 && r16 == 0) {
#pragma unroll
      for (int r = 0; r < 4; ++r)
        outL[(size_t)ks * BB * N + (size_t)b * N + q0 + h * 16 + quad * 4 + r] =
            lacc[h][r];
    }
#pragma unroll
    for (int ch = 0; ch < 4; ++ch)
#pragma unroll
      for (int r = 0; r < 4; ++r) {
        const size_t qi = (size_t)b * N + q0 + h * 16 + quad * 4 + r;
        if (KS == 1) {
          outF[qi * CC + ch * 16 + r16] = O[h][ch][r] / lacc[h][r];
        } else {
          outB[(size_t)ks * BB * N * CC + qi * CC + ch * 16 + r16] =
              f2bf_fast(O[h][ch][r]);
        }
      }
  }
}

// Merged dispatch — short blocks first (tail-fill), segment offsets ≡0 mod 8
// so b = bid&7 XCD grouping is preserved.
// [0,256) scale-2 NH=1/KS=2; [256,288) scale-4 NH=1/KS=1;
// [288,1312) scale-1 NH=2/KS=4. LDS 32KB -> 4 blocks/CU (VGPR cap 128).
__global__ __launch_bounds__(256, 4) void attn_all(
    const unsigned short* __restrict__ fh1, const unsigned short* __restrict__ fl1,
    const unsigned short* __restrict__ fv1,
    unsigned short* __restrict__ Op1, float* __restrict__ Lp1,
    const unsigned short* __restrict__ fh2, const unsigned short* __restrict__ fl2,
    const unsigned short* __restrict__ fv2,
    unsigned short* __restrict__ Op2, float* __restrict__ Lp2,
    const unsigned short* __restrict__ fh4, const unsigned short* __restrict__ fl4,
    const unsigned short* __restrict__ fv4, float* __restrict__ a4) {
  __shared__ __align__(16) unsigned short KVT[2][2 * 4096];
  const int bid = blockIdx.x;
  if (bid < 256) {
    attn_body<1, 2>(bid, fh2, fl2, fv2, nullptr, Op2, Lp2, 1024, &KVT[0][0]);
  } else if (bid < 288) {
    attn_body<1, 1>(bid - 256, fh4, fl4, fv4, a4, nullptr, nullptr, 256,
                    &KVT[0][0]);
  } else {
    attn_body<2, 4>(bid - 288, fh1, fl1, fv1, nullptr, Op1, Lp1, NPIX,
                    &KVT[0][0]);
  }
}

// ---------------------------------------------------------------------------
// final3: FUSED scale-1 combine (4 partials) + scale-2 combine (2 partials)
// + output assembly. Block = (b, y-row). (unchanged)
// ---------------------------------------------------------------------------
__global__ __launch_bounds__(256) void final3_kernel(
    const float* __restrict__ xin,
    const unsigned short* __restrict__ Op1, const float* __restrict__ Lp1,
    const unsigned short* __restrict__ Op2, const float* __restrict__ Lp2,
    const float* __restrict__ a4, float* __restrict__ out) {
  __shared__ float T[64][65];
  __shared__ float T2[64][66];
  const int tid = threadIdx.x;
  const int y = blockIdx.x & 63;
  const int b = blockIdx.x >> 6;
  const size_t S1 = (size_t)BB * NPIX * CC;
  const size_t T1 = (size_t)BB * NPIX;
  const size_t S2 = (size_t)BB * 1024 * CC;
  const size_t L2 = (size_t)BB * 1024;

  const float ty2 = y * 0.5f - 0.25f;
  const int iy2 = (int)floorf(ty2);
  const float wy2 = ty2 - iy2;
  const int iy20 = max(iy2, 0), iy21 = min(iy2 + 1, 31);

  const int nl = tid >> 2;             // 0..63
  const int ck = (tid & 3) * 16;       // c chunk

  {  // ---- phase 1: combine scale-1 row y (4 partials) ----
    const int n = y * 64 + nl;
    float lv = 0.f;
#pragma unroll
    for (int ks = 0; ks < 4; ++ks)
      lv += Lp1[(size_t)ks * T1 + (size_t)b * NPIX + n];
    const float inv = 1.f / lv;
    float v[16];
#pragma unroll
    for (int j = 0; j < 16; ++j) v[j] = 0.f;
#pragma unroll
    for (int ks = 0; ks < 4; ++ks) {
      const unsigned short* src =
          Op1 + (size_t)ks * S1 + ((size_t)b * NPIX + n) * CC + ck;
      const ushort8 u0 = *(const ushort8*)(src);
      const ushort8 u1 = *(const ushort8*)(src + 8);
#pragma unroll
      for (int j = 0; j < 8; ++j) {
        v[j]     += bf2f(u0[j]);
        v[8 + j] += bf2f(u1[j]);
      }
    }
#pragma unroll
    for (int j = 0; j < 16; ++j) T[ck + j][nl] = v[j] * inv;
  }
  {  // ---- phase 1b: combine scale-2 rows iy20 (nl<32) / iy21 (nl>=32) ----
    const int row = nl >> 5;
    const int ix  = nl & 31;
    const int n2  = (row == 0 ? iy20 : iy21) * 32 + ix;
    float lv = Lp2[(size_t)b * 1024 + n2] + Lp2[L2 + (size_t)b * 1024 + n2];
    const float inv = 1.f / lv;
    float v[16];
#pragma unroll
    for (int j = 0; j < 16; ++j) v[j] = 0.f;
#pragma unroll
    for (int ks = 0; ks < 2; ++ks) {
      const unsigned short* src =
          Op2 + (size_t)ks * S2 + ((size_t)b * 1024 + n2) * CC + ck;
      const ushort8 u0 = *(const ushort8*)(src);
      const ushort8 u1 = *(const ushort8*)(src + 8);
#pragma unroll
      for (int j = 0; j < 8; ++j) {
        v[j]     += bf2f(u0[j]);
        v[8 + j] += bf2f(u1[j]);
      }
    }
#pragma unroll
    for (int j = 0; j < 16; ++j) T2[ck + j][nl] = v[j] * inv;
  }
  __syncthreads();

  // ---- phase 2: assemble output row ----
  const int c  = tid >> 2;
  const int xk = (tid & 3) * 16;
  const float* xrow = xin + (((size_t)b * CC + c) * HH + y) * WW;
  float* orow = out + (((size_t)b * CC + c) * HH + y) * WW;

  const float ty4 = y * 0.25f - 0.375f;
  const int iy4 = (int)floorf(ty4);
  const float wy4 = ty4 - iy4;
  const int iy40 = max(iy4, 0), iy41 = min(iy4 + 1, 15);
  const float* b4 = a4 + (size_t)b * 256 * 64 + c;

#pragma unroll
  for (int j = 0; j < 16; ++j) {
    const int xx = xk + j;
    float r = xrow[xx] + T[c][xx];
    {  // scale 2 (rows pre-combined in T2: cols 0-31 = iy20, 32-63 = iy21)
      const float tx = xx * 0.5f - 0.25f;
      const int ix = (int)floorf(tx);
      const float wx = tx - ix;
      const int ix0 = max(ix, 0), ix1 = min(ix + 1, 31);
      const float v00 = T2[c][ix0],      v01 = T2[c][ix1];
      const float v10 = T2[c][32 + ix0], v11 = T2[c][32 + ix1];
      r += (1.f-wy2)*((1.f-wx)*v00 + wx*v01) + wy2*((1.f-wx)*v10 + wx*v11);
    }
    {  // scale 4
      const float tx = xx * 0.25f - 0.375f;
      const int ix = (int)floorf(tx);
      const float wx = tx - ix;
      const int ix0 = max(ix, 0), ix1 = min(ix + 1, 15);
      const float v00 = b4[(iy40*16+ix0)*64], v01 = b4[(iy40*16+ix1)*64];
      const float v10 = b4[(iy41*16+ix0)*64], v11 = b4[(iy41*16+ix1)*64];
      r += (1.f-wy4)*((1.f-wx)*v00 + wx*v01) + wy4*((1.f-wx)*v10 + wx*v11);
    }
    orow[xx] = r;
  }
}

// ---------------------------------------------------------------------------
extern "C" void kernel_launch(void* const* d_in, const int* in_sizes, int n_in,
                              void* d_out, int out_size, void* d_ws,
                              size_t ws_size, hipStream_t stream) {
  const float* x = (const float*)d_in[0];
  const float* w = (const float*)d_in[1];
  float* out = (float*)d_out;

  unsigned short* fh1 = (unsigned short*)d_ws;            // [8][4096][64] fp16 swz
  unsigned short* fl1 = fh1 + (size_t)BB*NPIX*CC;         // fp16 lo
  unsigned short* fv1 = fl1 + (size_t)BB*NPIX*CC;         // fp16 tile-major V^T
  unsigned short* fh2 = fv1 + (size_t)BB*NPIX*CC;         // [8][1024][64]
  unsigned short* fl2 = fh2 + (size_t)BB*1024*CC;
  unsigned short* fv2 = fl2 + (size_t)BB*1024*CC;
  unsigned short* fh4 = fv2 + (size_t)BB*1024*CC;         // [8][256][64]
  unsigned short* fl4 = fh4 + (size_t)BB*256*CC;
  unsigned short* fv4 = fl4 + (size_t)BB*256*CC;
  unsigned short* Op1 = fv4 + (size_t)BB*256*CC;          // [4][8][4096][64] bf16
  float* Lp1 = (float*)(Op1 + 4*(size_t)BB*NPIX*CC);      // [4][8][4096]
  unsigned short* Op2 = (unsigned short*)(Lp1 + 4*(size_t)BB*NPIX);  // [2][8][1024][64]
  float* Lp2 = (float*)(Op2 + 2*(size_t)BB*1024*CC);      // [2][8][1024]
  float* a4  = Lp2 + 2*(size_t)BB*1024;                   // [8][256][64] fp32

  // Dead-time aliases: WT (dead after conv_mfma) aliases Op2 (attn later)
  unsigned short* wth = (unsigned short*)Op2;             // 72 KB
  unsigned short* wtl = wth + 9*64*64;                    // 72 KB

  wprep_kernel<<<144, 256, 0, stream>>>(w, wth, wtl);
  conv_mfma<<<dim3(64, 8), 256, 0, stream>>>(x, wth, wtl, fh1, fl1, fv1);
  pools_kernel<<<2560, 256, 0, stream>>>(fh1, fl1, fh2, fl2, fv2, fh4, fl4, fv4);
  attn_all<<<1312, 256, 0, stream>>>(fh1, fl1, fv1, Op1, Lp1,
                                     fh2, fl2, fv2, Op2, Lp2,
                                     fh4, fl4, fv4, a4);
  final3_kernel<<<512, 256, 0, stream>>>(x, Op1, Lp1, Op2, Lp2, a4, out);
}